// Round 12
// baseline (2964.986 us; speedup 1.0000x reference)
//
#include <hip/hip_runtime.h>
#include <hip/hip_fp16.h>
#include <cstdint>

#define BSZ 4
#define LL  4096
#define DM  96
#define DI  192
#define NS  16
#define KK  4
#define C38 38

#define LC  64          // chunk length
#define NC  64          // number of chunks
#define NBLK (96 * NC)  // scanM blocks: 16 bk * 6 dgroups * 64 chunks
#define PADL 68         // LDS row stride (16B-aligned, breaks pow2)
#define PADU 196        // xdbl-tile LDS row stride (floats)

#define EXP2F(x) __builtin_amdgcn_exp2f(x)
#define LOG2F(x) __builtin_amdgcn_logf(x)
#define LOG2E 1.44269504f
#define LN2   0.69314718f

__device__ __forceinline__ float softplusf(float x) {
  float t = EXP2F(-fabsf(x) * LOG2E);
  return fmaxf(x, 0.f) + LN2 * LOG2F(1.f + t);
}
__device__ __forceinline__ float siluf(float x) {
  return x / (1.f + EXP2F(-x * LOG2E));
}

// ---------------- 0. region sort + weight transposes + scan-flag zeroing
__global__ __launch_bounds__(256) void k_sorttrans(const int* __restrict__ xm, int* __restrict__ rnk,
                                                   const float* __restrict__ Win,
                                                   const float* __restrict__ Wout,
                                                   float* __restrict__ WinT,
                                                   float* __restrict__ WoutT,
                                                   int* __restrict__ flags) {
  if (blockIdx.x < BSZ) {
    __shared__ int cnt[256];
    __shared__ int mloc[LL];
    int b = blockIdx.x, t = threadIdx.x;
    int c0 = 0;
    for (int i = 0; i < 16; ++i) {
      int p = t * 16 + i;
      int m = xm[b * LL + p];
      mloc[p] = m;
      c0 += (m == 0);
    }
    cnt[t] = c0;
    __syncthreads();
    for (int off = 1; off < 256; off <<= 1) {
      int v = (t >= off) ? cnt[t - off] : 0;
      __syncthreads();
      cnt[t] += v;
      __syncthreads();
    }
    int n0 = cnt[255];
    int zb = cnt[t] - c0;
    for (int i = 0; i < 16; ++i) {
      int p = t * 16 + i;
      int r;
      if (mloc[p] == 0) { r = zb; zb++; }
      else              { r = n0 + p - zb; }
      rnk[b * LL + p] = r;
    }
  } else {
    int e = (blockIdx.x - BSZ) * 256 + threadIdx.x;
    if (e < 384 * DM) {
      int t = e / 384, j = e % 384;
      WinT[e] = Win[(size_t)j * DM + t];
    } else if (e < 384 * DM + DM * DI) {
      int e2 = e - 384 * DM;
      int t = e2 / DM, dm = e2 % DM;
      WoutT[e2] = Wout[(size_t)dm * DI + t];
    } else {
      int fi = e - (384 * DM + DM * DI);
      if (fi < NBLK) flags[fi] = 0;
    }
  }
}

// ---------------- 1. in_proj (b128 LDS reads: 4 t-steps per ds_read)
#define PPB 16
__global__ __launch_bounds__(384) void k_inproj(const float* __restrict__ x,
                                                const float* __restrict__ WinT,
                                                float* __restrict__ xh,
                                                float* __restrict__ z) {
  __shared__ __align__(16) float xv[PPB][DM];
  int j  = threadIdx.x;
  int p0 = blockIdx.x * PPB;
  for (int e = j; e < PPB * DM; e += 384) {
    int pp = e / DM, tt = e % DM;
    xv[pp][tt] = x[(size_t)(p0 + pp) * DM + tt];
  }
  __syncthreads();
  float acc[PPB];
#pragma unroll
  for (int pp = 0; pp < PPB; ++pp) acc[pp] = 0.f;
  for (int t = 0; t < DM; t += 4) {
    float w0 = WinT[(size_t)(t + 0) * 384 + j];
    float w1 = WinT[(size_t)(t + 1) * 384 + j];
    float w2 = WinT[(size_t)(t + 2) * 384 + j];
    float w3 = WinT[(size_t)(t + 3) * 384 + j];
#pragma unroll
    for (int pp = 0; pp < PPB; ++pp) {
      float4 xq = *(const float4*)&xv[pp][t];
      acc[pp] = fmaf(xq.x, w0, acc[pp]);
      acc[pp] = fmaf(xq.y, w1, acc[pp]);
      acc[pp] = fmaf(xq.z, w2, acc[pp]);
      acc[pp] = fmaf(xq.w, w3, acc[pp]);
    }
  }
#pragma unroll
  for (int pp = 0; pp < PPB; ++pp) {
    size_t p = (size_t)(p0 + pp);
    if (j < DI) xh[p * DI + j] = acc[pp];
    else        z[p * DI + (j - DI)] = acc[pp];
  }
}

// ---------------- 2. depthwise 3x3 conv + silu; writes xc + both gathered orders
__global__ __launch_bounds__(192) void k_conv(const float* __restrict__ xh,
                                              const float* __restrict__ w3,
                                              const float* __restrict__ cb,
                                              const int* __restrict__ rnk,
                                              float* __restrict__ xc,
                                              float* __restrict__ xg0,
                                              float* __restrict__ xg1) {
  int p = blockIdx.x; int b = p >> 12; int l = p & 4095;
  int h = l >> 6, w = l & 63;
  int c = threadIdx.x;
  float wr[9];
#pragma unroll
  for (int j = 0; j < 9; ++j) wr[j] = w3[c * 9 + j];
  float acc = cb[c];
#pragma unroll
  for (int kh = 0; kh < 3; ++kh) {
    int hh = h + kh - 1;
    if ((unsigned)hh >= 64u) continue;
#pragma unroll
    for (int kw = 0; kw < 3; ++kw) {
      int ww2 = w + kw - 1;
      if ((unsigned)ww2 >= 64u) continue;
      acc = fmaf(xh[((size_t)b * LL + (hh << 6) + ww2) * DI + c], wr[kh * 3 + kw], acc);
    }
  }
  float v = siluf(acc);
  xc[(size_t)p * DI + c] = v;
  int r = rnk[b * LL + l];
  xg0[((size_t)b * LL + r) * DI + c] = v;
  int lT = ((l & 63) << 6) | (l >> 6);
  xg1[((size_t)b * LL + lT) * DI + c] = v;
}

// ---------------- 5. x_dbl: weight-stationary regs, LDS-broadcast U, 32-row tiles
__global__ __launch_bounds__(192) void k_xdbl(const float* __restrict__ xg0,
                                              const float* __restrict__ xg1,
                                              const float* __restrict__ xpw,
                                              float* __restrict__ xdblT) {
  __shared__ float sU[32][PADU];
  int bid = blockIdx.x;
  int lg = bid & 127;
  int bsrc = bid >> 7;
  int b = bsrc >> 1, src = bsrc & 1;
  int l0 = lg * 32;
  int tid = threadIdx.x;
  const float* xg = src ? xg1 : xg0;
  const float* gsrc = xg + ((size_t)b * LL + l0) * DI;
  for (int e = tid; e < 32 * 48; e += 192) {
    int row = e / 48, c4 = e % 48;
    *(float4*)&sU[row][c4 * 4] = *(const float4*)(gsrc + (size_t)row * DI + c4 * 4);
  }
  int c = tid >> 2, dseg = tid & 3;
  bool active = (c < C38);
  int cs = active ? c : 0;
  int k0 = src, k1 = src + 2;
  const float4* wp0 = (const float4*)(xpw + ((size_t)k0 * C38 + cs) * DI + dseg * 48);
  const float4* wp1 = (const float4*)(xpw + ((size_t)k1 * C38 + cs) * DI + dseg * 48);
  float4 w0[12], w1[12];
#pragma unroll
  for (int j = 0; j < 12; ++j) { w0[j] = wp0[j]; w1[j] = wp1[j]; }
  float* od0 = xdblT + ((size_t)(b * 4 + k0) * C38 + cs) * LL;
  float* od1 = xdblT + ((size_t)(b * 4 + k1) * C38 + cs) * LL;
  __syncthreads();
  for (int p = 0; p < 32; ++p) {
    float a0 = 0.f, a1 = 0.f;
    const float* ur = &sU[p][dseg * 48];
#pragma unroll
    for (int j = 0; j < 12; ++j) {
      float4 u = *(const float4*)(ur + j * 4);
      a0 = fmaf(u.x, w0[j].x, a0); a1 = fmaf(u.x, w1[j].x, a1);
      a0 = fmaf(u.y, w0[j].y, a0); a1 = fmaf(u.y, w1[j].y, a1);
      a0 = fmaf(u.z, w0[j].z, a0); a1 = fmaf(u.z, w1[j].z, a1);
      a0 = fmaf(u.w, w0[j].w, a0); a1 = fmaf(u.w, w1[j].w, a1);
    }
    a0 += __shfl_xor(a0, 1, 64); a0 += __shfl_xor(a0, 2, 64);
    a1 += __shfl_xor(a1, 1, 64); a1 += __shfl_xor(a1, 2, 64);
    if (dseg == 0 && active) {
      int l = l0 + p;
      od0[l] = a0;
      od1[LL - 1 - l] = a1;
    }
  }
}

// ---------------- 6. merged scan: aggregate + decoupled look-back + output
__global__ __launch_bounds__(512) void k_scanM(const float* __restrict__ xg0,
                                               const float* __restrict__ xg1,
                                               const float* __restrict__ xdblT,
                                               const float* __restrict__ dtw,
                                               const float* __restrict__ dtb,
                                               const float* __restrict__ Alogs,
                                               const float* __restrict__ Ds,
                                               float* __restrict__ Pagg,
                                               float* __restrict__ Sagg,
                                               float* __restrict__ Inc,
                                               int* __restrict__ flags,
                                               __half* __restrict__ outy) {
  __shared__ float sX[C38][PADL];    // 0..5 dts, 6..21 B, 22..37 C
  __shared__ float sU[32][PADL];
  __shared__ float sDL[32][PADL];
  __shared__ float sDU[32][PADL];
  int blk = blockIdx.x;
  int cb = blk / NC, c = blk % NC;
  int bk = cb / 6, dg2 = cb % 6;
  int b = bk >> 2, k = bk & 3, d0 = dg2 * 32;
  int tid = threadIdx.x, ci = tid >> 4, n = tid & 15, d = d0 + ci;
  int l0 = c * LC;
  const float* xg = (k & 1) ? xg1 : xg0;
  // stage all 38 x_dbl rows
  for (int e = tid; e < C38 * 16; e += 512) {
    int r = e >> 4, c4 = e & 15;
    float4 v = *(const float4*)(xdblT + ((size_t)(bk * C38 + r) * LL + l0 + c4 * 4));
    *(float4*)&sX[r][c4 * 4] = v;
  }
  // stage U: one float4 per thread
  {
    int l = tid >> 3, dq = tid & 7;
    int ll = l0 + l;
    int ls = (k & 2) ? (LL - 1 - ll) : ll;
    float4 v = *(const float4*)(xg + ((size_t)b * LL + ls) * DI + d0 + dq * 4);
    sU[dq * 4 + 0][l] = v.x;
    sU[dq * 4 + 1][l] = v.y;
    sU[dq * 4 + 2][l] = v.z;
    sU[dq * 4 + 3][l] = v.w;
  }
  float wr[6];
#pragma unroll
  for (int r = 0; r < 6; ++r) wr[r] = dtw[(size_t)(k * DI + d) * 6 + r];
  float bias = dtb[k * DI + d];
  float a2 = -__expf(Alogs[(size_t)(k * DI + d) * NS + n]) * LOG2E;
  float Dv = Ds[k * DI + d];
  __syncthreads();
  // dt-proj + per-thread dl partial sum
  float tsum = 0.f;
#pragma unroll
  for (int j = 0; j < 4; ++j) {
    int l = n + 16 * j;
    float acc = bias;
#pragma unroll
    for (int r = 0; r < 6; ++r) acc = fmaf(sX[r][l], wr[r], acc);
    float dl = softplusf(acc);
    sDL[ci][l] = dl;
    sDU[ci][l] = dl * sU[ci][l];
    tsum += dl;
  }
  // Tot over the 16 n-lanes of this d-row
  tsum += __shfl_xor(tsum, 1, 64);
  tsum += __shfl_xor(tsum, 2, 64);
  tsum += __shfl_xor(tsum, 4, 64);
  tsum += __shfl_xor(tsum, 8, 64);
  float Pv = EXP2F(a2 * tsum);
  __syncthreads();
  // pass 1: chunk-local state from 0 (no outputs)
  float S = 0.f;
#pragma unroll 4
  for (int l4 = 0; l4 < 16; ++l4) {
    float4 DL4 = *(const float4*)&sDL[ci][l4 * 4];
    float4 DU4 = *(const float4*)&sDU[ci][l4 * 4];
    float4 B4  = *(const float4*)&sX[6 + n][l4 * 4];
    S = fmaf(S, EXP2F(DL4.x * a2), DU4.x * B4.x);
    S = fmaf(S, EXP2F(DL4.y * a2), DU4.y * B4.y);
    S = fmaf(S, EXP2F(DL4.z * a2), DU4.z * B4.z);
    S = fmaf(S, EXP2F(DL4.w * a2), DU4.w * B4.w);
  }
  size_t gidx = (size_t)blk * 512 + tid;
  Pagg[gidx] = Pv;
  Sagg[gidx] = S;
  __threadfence();
  __syncthreads();
  if (tid == 0) atomicExch(&flags[blk], 1);
  // look-back
  float H = 0.f;
  if (c > 0) {
    float accP = 1.f, accS = 0.f;
    int fbase = cb * NC;
    int j = c - 1;
    while (true) {
      int f = 0;
      if ((tid & 63) == 0) {
        while ((f = atomicAdd(&flags[fbase + j], 0)) == 0) {
          __builtin_amdgcn_s_sleep(2);
        }
      }
      f = __shfl(f, 0, 64);
      size_t pidx = (size_t)(fbase + j) * 512 + tid;
      if (f == 2) {
        float I = ((volatile const float*)Inc)[pidx];
        H = accS + accP * I;
        break;
      } else {
        float Pj = ((volatile const float*)Pagg)[pidx];
        float Sj = ((volatile const float*)Sagg)[pidx];
        accS = accS + accP * Sj;
        accP = accP * Pj;
        if (j == 0) { H = accS; break; }
        --j;
      }
    }
  }
  Inc[gidx] = S + Pv * H;
  __threadfence();
  __syncthreads();
  if (tid == 0) atomicExch(&flags[blk], 2);
  // pass 2: outputs with correct initial state
  float h = H;
  bool k8 = (n & 8) != 0, k4 = (n & 4) != 0, k2 = (n & 2) != 0, k1 = (n & 1) != 0;
  __half* orow = outy + ((size_t)bk * LL + l0) * DI;
  for (int w16 = 0; w16 < 4; ++w16) {
    float acc[16];
#pragma unroll
    for (int q = 0; q < 4; ++q) {
      int l = w16 * 16 + q * 4;
      float4 DL4 = *(const float4*)&sDL[ci][l];
      float4 DU4 = *(const float4*)&sDU[ci][l];
      float4 B4  = *(const float4*)&sX[6 + n][l];
      float4 C4  = *(const float4*)&sX[22 + n][l];
      h = fmaf(h, EXP2F(DL4.x * a2), DU4.x * B4.x); acc[q * 4 + 0] = h * C4.x;
      h = fmaf(h, EXP2F(DL4.y * a2), DU4.y * B4.y); acc[q * 4 + 1] = h * C4.y;
      h = fmaf(h, EXP2F(DL4.z * a2), DU4.z * B4.z); acc[q * 4 + 2] = h * C4.z;
      h = fmaf(h, EXP2F(DL4.w * a2), DU4.w * B4.w); acc[q * 4 + 3] = h * C4.w;
    }
    float b8[8];
#pragma unroll
    for (int t = 0; t < 8; ++t) {
      float lo = acc[t], hi = acc[t + 8];
      float r = __shfl_xor(k8 ? lo : hi, 8, 64);
      b8[t] = (k8 ? hi : lo) + r;
    }
    float b4v[4];
#pragma unroll
    for (int t = 0; t < 4; ++t) {
      float lo = b8[t], hi = b8[t + 4];
      float r = __shfl_xor(k4 ? lo : hi, 4, 64);
      b4v[t] = (k4 ? hi : lo) + r;
    }
    float b2v[2];
#pragma unroll
    for (int t = 0; t < 2; ++t) {
      float lo = b4v[t], hi = b4v[t + 2];
      float r = __shfl_xor(k2 ? lo : hi, 2, 64);
      b2v[t] = (k2 ? hi : lo) + r;
    }
    float lo = b2v[0], hi = b2v[1];
    float r = __shfl_xor(k1 ? lo : hi, 1, 64);
    float y = (k1 ? hi : lo) + r;
    int lw = w16 * 16 + n;
    y = fmaf(sU[ci][lw], Dv, y);
    orow[(size_t)lw * DI + d0 + ci] = __float2half(y);
  }
}

// ---------------- 8. pooled partial sums
__global__ __launch_bounds__(192) void k_pool(const float* __restrict__ xc, float* __restrict__ partial) {
  int blk = blockIdx.x; int b = blk >> 5; int s = blk & 31;
  int d = threadIdx.x;
  const float* p = xc + ((size_t)b * LL + s * 128) * DI + d;
  float acc = 0.f;
#pragma unroll 8
  for (int l = 0; l < 128; ++l) acc += p[(size_t)l * DI];
  partial[(size_t)blk * DI + d] = acc;
}

// ---------------- 9+10. channel prep + scan + catt
__global__ __launch_bounds__(512) void k_ccomb(const float* __restrict__ partial,
                                               const float* __restrict__ cinw,
                                               const float* __restrict__ cinb,
                                               const float* __restrict__ xcw,
                                               const float* __restrict__ dtcw,
                                               const float* __restrict__ dtcb,
                                               const float* __restrict__ Aclogs,
                                               const float* __restrict__ Dsc,
                                               const float* __restrict__ coutw,
                                               const float* __restrict__ coutb,
                                               float* __restrict__ uc, float* __restrict__ dc,
                                               float* __restrict__ Bc, float* __restrict__ Cc,
                                               float* __restrict__ catt) {
  __shared__ float ycs[BSZ][2][4][DI];
  int t = threadIdx.x;
  for (int g = t; g < BSZ * 2 * DI; g += 512) {
    int l = g % DI; int k = (g / DI) & 1; int b = g / (2 * DI);
    int lsrc = k ? (DI - 1 - l) : l;
    float pv = 0.f;
#pragma unroll 8
    for (int s = 0; s < 32; ++s) pv += partial[(size_t)(b * 32 + s) * DI + lsrc];
    pv *= (1.f / 4096.f);
    float u[4];
#pragma unroll
    for (int i = 0; i < 4; ++i) u[i] = fmaf(pv, cinw[i], cinb[i]);
    int pos = (b * 2 + k) * DI + l;
    float db[C38];
#pragma unroll
    for (int c = 0; c < C38; ++c) {
      float s = 0.f;
#pragma unroll
      for (int i = 0; i < 4; ++i) s = fmaf(u[i], xcw[(k * C38 + c) * 4 + i], s);
      db[c] = s;
    }
#pragma unroll
    for (int i = 0; i < 4; ++i) uc[pos * 4 + i] = u[i];
#pragma unroll
    for (int i = 0; i < 4; ++i) {
      float tt = dtcb[k * 4 + i];
#pragma unroll
      for (int r = 0; r < 6; ++r) tt = fmaf(db[r], dtcw[(k * 4 + i) * 6 + r], tt);
      dc[pos * 4 + i] = softplusf(tt);
    }
#pragma unroll
    for (int n = 0; n < NS; ++n) Bc[pos * NS + n] = db[6 + n];
#pragma unroll
    for (int n = 0; n < NS; ++n) Cc[pos * NS + n] = db[22 + n];
  }
  __threadfence_block();
  __syncthreads();
  int chain = t >> 4;
  int n = t & 15;
  int b = chain >> 3; int k = (chain >> 2) & 1; int i = chain & 3;
  float a  = -__expf(Aclogs[(k * 4 + i) * NS + n]);
  float Dv = Dsc[k * 4 + i];
  const float* dp = dc + (size_t)((b * 2 + k) * DI) * 4 + i;
  const float* up = uc + (size_t)((b * 2 + k) * DI) * 4 + i;
  const float* bp = Bc + (size_t)((b * 2 + k) * DI) * NS + n;
  const float* cp = Cc + (size_t)((b * 2 + k) * DI) * NS + n;
  float h = 0.f;
  float qdA[8], quA[8], qbA[8], qcA[8];
  float qdB[8], quB[8], qbB[8], qcB[8];
#pragma unroll
  for (int j = 0; j < 8; ++j) {
    qdA[j] = dp[j * 4]; quA[j] = up[j * 4];
    qbA[j] = bp[j * 16]; qcA[j] = cp[j * 16];
  }
  for (int r = 0; r < 24; r += 2) {
    int lB = (r + 1) * 8;
#pragma unroll
    for (int j = 0; j < 8; ++j) {
      qdB[j] = dp[(lB + j) * 4]; quB[j] = up[(lB + j) * 4];
      qbB[j] = bp[(lB + j) * 16]; qcB[j] = cp[(lB + j) * 16];
    }
#pragma unroll
    for (int j = 0; j < 8; ++j) {
      float dl = qdA[j], ul = quA[j], Bv = qbA[j], Cv = qcA[j];
      h = fmaf(h, __expf(dl * a), dl * ul * Bv);
      float yv = h * Cv;
      yv += __shfl_xor(yv, 1, 64);
      yv += __shfl_xor(yv, 2, 64);
      yv += __shfl_xor(yv, 4, 64);
      yv += __shfl_xor(yv, 8, 64);
      if (n == 0) ycs[b][k][i][r * 8 + j] = yv + ul * Dv;
    }
    if (r + 2 < 24) {
      int lA = (r + 2) * 8;
#pragma unroll
      for (int j = 0; j < 8; ++j) {
        qdA[j] = dp[(lA + j) * 4]; quA[j] = up[(lA + j) * 4];
        qbA[j] = bp[(lA + j) * 16]; qcA[j] = cp[(lA + j) * 16];
      }
    }
#pragma unroll
    for (int j = 0; j < 8; ++j) {
      float dl = qdB[j], ul = quB[j], Bv = qbB[j], Cv = qcB[j];
      h = fmaf(h, __expf(dl * a), dl * ul * Bv);
      float yv = h * Cv;
      yv += __shfl_xor(yv, 1, 64);
      yv += __shfl_xor(yv, 2, 64);
      yv += __shfl_xor(yv, 4, 64);
      yv += __shfl_xor(yv, 8, 64);
      if (n == 0) ycs[b][k][i][(r + 1) * 8 + j] = yv + ul * Dv;
    }
  }
  __syncthreads();
  float cw[4];
#pragma unroll
  for (int q = 0; q < 4; ++q) cw[q] = coutw[q];
  float cb0 = coutb[0];
  for (int e = t; e < BSZ * DI; e += 512) {
    int bb = e / DI, ll = e % DI;
    float s = cb0;
#pragma unroll
    for (int q = 0; q < 4; ++q)
      s = fmaf(ycs[bb][0][q][ll] + ycs[bb][1][q][DI - 1 - ll], cw[q], s);
    catt[bb * DI + ll] = s;
  }
}

// ---------------- 11. final fuse (fp16 outy reads, weight-amortized out-proj)
__global__ __launch_bounds__(512) void k_final(const __half* __restrict__ outy,
                                               const float* __restrict__ xc,
                                               const float* __restrict__ z,
                                               const float* __restrict__ catt,
                                               const float* __restrict__ onw,
                                               const float* __restrict__ onb,
                                               const float* __restrict__ cnw,
                                               const float* __restrict__ cnb,
                                               const float* __restrict__ WoutT,
                                               float* __restrict__ out) {
  __shared__ __align__(16) float sComb[8][DI + 4];
  int w = threadIdx.x >> 6, lane = threadIdx.x & 63;
  int p = blockIdx.x * 8 + w;
  int b = p >> 12, l = p & 4095;
  int lT = ((l & 63) << 6) | (l >> 6);
  size_t base = (size_t)b * KK * LL;
  const __half* r0 = outy + (base + l) * DI;
  const __half* r1 = outy + (base + 2 * LL + (LL - 1 - l)) * DI;
  const __half* r2 = outy + (base + LL + lT) * DI;
  const __half* r3 = outy + (base + 3 * LL + (LL - 1 - lT)) * DI;
  const float* xcr = xc + ((size_t)b * LL + l) * DI;
  const float* zr  = z + ((size_t)b * LL + l) * DI;
  const float* cattr = catt + b * DI;
  float ys[3], xch[3], zv[3];
  float s1 = 0.f, s2 = 0.f, t1 = 0.f, t2 = 0.f;
#pragma unroll
  for (int j = 0; j < 3; ++j) {
    int d = lane + 64 * j;
    float v = __half2float(r0[d]) + __half2float(r1[d])
            + __half2float(r2[d]) + __half2float(r3[d]);
    ys[j] = v; s1 += v; s2 += v * v;
    float xv = xcr[d] * cattr[d];
    xch[j] = xv; t1 += xv; t2 += xv * xv;
    zv[j] = zr[d];
  }
#pragma unroll
  for (int m = 1; m < 64; m <<= 1) {
    s1 += __shfl_xor(s1, m, 64);
    s2 += __shfl_xor(s2, m, 64);
    t1 += __shfl_xor(t1, m, 64);
    t2 += __shfl_xor(t2, m, 64);
  }
  float mu  = s1 * (1.f / DI);
  float var = s2 * (1.f / DI) - mu * mu;
  float rstd = rsqrtf(var + 1e-5f);
  float mu2  = t1 * (1.f / DI);
  float var2 = t2 * (1.f / DI) - mu2 * mu2;
  float rstd2 = rsqrtf(var2 + 1e-5f);
#pragma unroll
  for (int j = 0; j < 3; ++j) {
    int d = lane + 64 * j;
    float yln  = fmaf((ys[j] - mu) * rstd, onw[d], onb[d]);
    float xchn = fmaf((xch[j] - mu2) * rstd2, cnw[d], cnb[d]);
    sComb[w][d] = (yln + xchn) * siluf(zv[j]);
  }
  __syncthreads();
  if (threadIdx.x < DM) {
    int dm = threadIdx.x;
    float acc[8];
#pragma unroll
    for (int p8 = 0; p8 < 8; ++p8) acc[p8] = 0.f;
    for (int t = 0; t < DI; t += 4) {
      float w0 = WoutT[(size_t)(t + 0) * DM + dm];
      float w1 = WoutT[(size_t)(t + 1) * DM + dm];
      float w2 = WoutT[(size_t)(t + 2) * DM + dm];
      float w3 = WoutT[(size_t)(t + 3) * DM + dm];
#pragma unroll
      for (int p8 = 0; p8 < 8; ++p8) {
        float4 cv = *(const float4*)&sComb[p8][t];
        acc[p8] = fmaf(cv.x, w0, acc[p8]);
        acc[p8] = fmaf(cv.y, w1, acc[p8]);
        acc[p8] = fmaf(cv.z, w2, acc[p8]);
        acc[p8] = fmaf(cv.w, w3, acc[p8]);
      }
    }
#pragma unroll
    for (int p8 = 0; p8 < 8; ++p8)
      out[(size_t)(blockIdx.x * 8 + p8) * DM + dm] = acc[p8];
  }
}

extern "C" void kernel_launch(void* const* d_in, const int* in_sizes, int n_in,
                              void* d_out, int out_size, void* d_ws, size_t ws_size,
                              hipStream_t stream) {
  const float* x     = (const float*)d_in[0];
  const int*   xm    = (const int*)  d_in[1];
  const float* Win   = (const float*)d_in[2];
  const float* w3    = (const float*)d_in[3];
  const float* cbia  = (const float*)d_in[4];
  const float* xpw   = (const float*)d_in[5];
  const float* dtw   = (const float*)d_in[6];
  const float* dtb   = (const float*)d_in[7];
  const float* Alogs = (const float*)d_in[8];
  const float* Ds    = (const float*)d_in[9];
  const float* onw   = (const float*)d_in[10];
  const float* onb   = (const float*)d_in[11];
  const float* Wout  = (const float*)d_in[12];
  const float* cinw  = (const float*)d_in[13];
  const float* cinb  = (const float*)d_in[14];
  const float* coutw = (const float*)d_in[15];
  const float* coutb = (const float*)d_in[16];
  const float* xcw   = (const float*)d_in[17];
  const float* Dsc   = (const float*)d_in[18];
  const float* Aclog = (const float*)d_in[19];
  const float* dtcw  = (const float*)d_in[20];
  const float* dtcb  = (const float*)d_in[21];
  const float* cnw   = (const float*)d_in[22];
  const float* cnb   = (const float*)d_in[23];
  float* out = (float*)d_out;

  float* ws = (float*)d_ws;
  size_t o = 0;
  float* xdblT = ws + o; o += (size_t)BSZ * KK * C38 * LL;
  float* oyreg = ws + o; o += (size_t)BSZ * KK * LL * DI / 2;  // outy as fp16
  float* xc    = ws + o; o += (size_t)BSZ * LL * DI;
  float* z     = ws + o; o += (size_t)BSZ * LL * DI;
  float* xg0   = ws + o; o += (size_t)BSZ * LL * DI;
  float* xg1   = ws + o; o += (size_t)BSZ * LL * DI;
  float* Pagg  = ws + o; o += (size_t)NBLK * 512;
  float* Sagg  = ws + o; o += (size_t)NBLK * 512;
  float* Inc   = ws + o; o += (size_t)NBLK * 512;
  float* partial = ws + o; o += BSZ * 32 * DI;
  float* uc    = ws + o; o += BSZ * 2 * DI * 4;
  float* dc    = ws + o; o += BSZ * 2 * DI * 4;
  float* Bc    = ws + o; o += BSZ * 2 * DI * NS;
  float* Cc    = ws + o; o += BSZ * 2 * DI * NS;
  float* catt  = ws + o; o += BSZ * DI;
  float* WinT  = ws + o; o += 384 * DM;
  float* WoutT = ws + o; o += DM * DI;
  int*   rnk   = (int*)(ws + o); o += BSZ * LL;
  int*   flags = (int*)(ws + o); o += NBLK;
  __half* outy = (__half*)oyreg;   // fp16 outy buffer
  float* xh    = oyreg;            // alias: xh dead before k_scanM writes outy

  int totElems = 384 * DM + DM * DI + NBLK;
  int auxBlocks = (totElems + 255) / 256;
  k_sorttrans<<<BSZ + auxBlocks, 256, 0, stream>>>(xm, rnk, Win, Wout, WinT, WoutT, flags);
  k_inproj<<<(BSZ * LL) / PPB, 384, 0, stream>>>(x, WinT, xh, z);
  k_conv  <<<BSZ * LL, 192, 0, stream>>>(xh, w3, cbia, rnk, xc, xg0, xg1);
  k_xdbl  <<<BSZ * 2 * 128, 192, 0, stream>>>(xg0, xg1, xpw, xdblT);
  k_scanM <<<NBLK, 512, 0, stream>>>(xg0, xg1, xdblT, dtw, dtb, Alogs, Ds, Pagg, Sagg, Inc, flags, outy);
  k_pool  <<<BSZ * 32, 192, 0, stream>>>(xc, partial);
  k_ccomb <<<1, 512, 0, stream>>>(partial, cinw, cinb, xcw, dtcw, dtcb, Aclog, Dsc, coutw, coutb, uc, dc, Bc, Cc, catt);
  k_final <<<(BSZ * LL) / 8, 512, 0, stream>>>(outy, xc, z, catt, onw, onb, cnw, cnb, WoutT, out);
}

// Round 13
// 424.529 us; speedup vs baseline: 6.9842x; 6.9842x over previous
//
#include <hip/hip_runtime.h>
#include <hip/hip_fp16.h>
#include <cstdint>

#define BSZ 4
#define LL  4096
#define DM  96
#define DI  192
#define NS  16
#define KK  4
#define C38 38

#define LC  64          // chunk length
#define NC  64          // number of chunks
#define ST  49152       // chains*NS = 3072*16
#define PADL 68         // LDS row stride (16B-aligned, breaks pow2)
#define PADU 196        // xdbl-tile LDS row stride (floats)

#define EXP2F(x) __builtin_amdgcn_exp2f(x)
#define LOG2F(x) __builtin_amdgcn_logf(x)
#define LOG2E 1.44269504f
#define LN2   0.69314718f

__device__ __forceinline__ float softplusf(float x) {
  float t = EXP2F(-fabsf(x) * LOG2E);
  return fmaxf(x, 0.f) + LN2 * LOG2F(1.f + t);
}
__device__ __forceinline__ float siluf(float x) {
  return x / (1.f + EXP2F(-x * LOG2E));
}

// ---------------- 0. region sort (inverse perm rnk) + weight transposes
__global__ __launch_bounds__(256) void k_sorttrans(const int* __restrict__ xm, int* __restrict__ rnk,
                                                   const float* __restrict__ Win,
                                                   const float* __restrict__ Wout,
                                                   float* __restrict__ WinT,
                                                   float* __restrict__ WoutT) {
  if (blockIdx.x < BSZ) {
    __shared__ int cnt[256];
    __shared__ int mloc[LL];
    int b = blockIdx.x, t = threadIdx.x;
    int c0 = 0;
    for (int i = 0; i < 16; ++i) {
      int p = t * 16 + i;
      int m = xm[b * LL + p];
      mloc[p] = m;
      c0 += (m == 0);
    }
    cnt[t] = c0;
    __syncthreads();
    for (int off = 1; off < 256; off <<= 1) {
      int v = (t >= off) ? cnt[t - off] : 0;
      __syncthreads();
      cnt[t] += v;
      __syncthreads();
    }
    int n0 = cnt[255];
    int zb = cnt[t] - c0;
    for (int i = 0; i < 16; ++i) {
      int p = t * 16 + i;
      int r;
      if (mloc[p] == 0) { r = zb; zb++; }
      else              { r = n0 + p - zb; }
      rnk[b * LL + p] = r;
    }
  } else {
    int e = (blockIdx.x - BSZ) * 256 + threadIdx.x;
    if (e < 384 * DM) {
      int t = e / 384, j = e % 384;
      WinT[e] = Win[(size_t)j * DM + t];
    } else {
      int e2 = e - 384 * DM;
      if (e2 < DM * DI) {
        int t = e2 / DM, dm = e2 % DM;
        WoutT[e2] = Wout[(size_t)dm * DI + t];
      }
    }
  }
}

// ---------------- 1. in_proj (b128 LDS reads: 4 t-steps per ds_read)
#define PPB 16
__global__ __launch_bounds__(384) void k_inproj(const float* __restrict__ x,
                                                const float* __restrict__ WinT,
                                                float* __restrict__ xh,
                                                float* __restrict__ z) {
  __shared__ __align__(16) float xv[PPB][DM];
  int j  = threadIdx.x;
  int p0 = blockIdx.x * PPB;
  for (int e = j; e < PPB * DM; e += 384) {
    int pp = e / DM, tt = e % DM;
    xv[pp][tt] = x[(size_t)(p0 + pp) * DM + tt];
  }
  __syncthreads();
  float acc[PPB];
#pragma unroll
  for (int pp = 0; pp < PPB; ++pp) acc[pp] = 0.f;
  for (int t = 0; t < DM; t += 4) {
    float w0 = WinT[(size_t)(t + 0) * 384 + j];
    float w1 = WinT[(size_t)(t + 1) * 384 + j];
    float w2 = WinT[(size_t)(t + 2) * 384 + j];
    float w3 = WinT[(size_t)(t + 3) * 384 + j];
#pragma unroll
    for (int pp = 0; pp < PPB; ++pp) {
      float4 xq = *(const float4*)&xv[pp][t];
      acc[pp] = fmaf(xq.x, w0, acc[pp]);
      acc[pp] = fmaf(xq.y, w1, acc[pp]);
      acc[pp] = fmaf(xq.z, w2, acc[pp]);
      acc[pp] = fmaf(xq.w, w3, acc[pp]);
    }
  }
#pragma unroll
  for (int pp = 0; pp < PPB; ++pp) {
    size_t p = (size_t)(p0 + pp);
    if (j < DI) xh[p * DI + j] = acc[pp];
    else        z[p * DI + (j - DI)] = acc[pp];
  }
}

// ---------------- 2. depthwise 3x3 conv + silu; writes xc + both gathered orders
__global__ __launch_bounds__(192) void k_conv(const float* __restrict__ xh,
                                              const float* __restrict__ w3,
                                              const float* __restrict__ cb,
                                              const int* __restrict__ rnk,
                                              float* __restrict__ xc,
                                              float* __restrict__ xg0,
                                              float* __restrict__ xg1) {
  int p = blockIdx.x; int b = p >> 12; int l = p & 4095;
  int h = l >> 6, w = l & 63;
  int c = threadIdx.x;
  float wr[9];
#pragma unroll
  for (int j = 0; j < 9; ++j) wr[j] = w3[c * 9 + j];
  float acc = cb[c];
#pragma unroll
  for (int kh = 0; kh < 3; ++kh) {
    int hh = h + kh - 1;
    if ((unsigned)hh >= 64u) continue;
#pragma unroll
    for (int kw = 0; kw < 3; ++kw) {
      int ww2 = w + kw - 1;
      if ((unsigned)ww2 >= 64u) continue;
      acc = fmaf(xh[((size_t)b * LL + (hh << 6) + ww2) * DI + c], wr[kh * 3 + kw], acc);
    }
  }
  float v = siluf(acc);
  xc[(size_t)p * DI + c] = v;
  int r = rnk[b * LL + l];
  xg0[((size_t)b * LL + r) * DI + c] = v;
  int lT = ((l & 63) << 6) | (l >> 6);
  xg1[((size_t)b * LL + lT) * DI + c] = v;
}

// ---------------- 5. x_dbl: weight-stationary regs, LDS-broadcast U, 32-row tiles
__global__ __launch_bounds__(192) void k_xdbl(const float* __restrict__ xg0,
                                              const float* __restrict__ xg1,
                                              const float* __restrict__ xpw,
                                              float* __restrict__ xdblT) {
  __shared__ float sU[32][PADU];
  int bid = blockIdx.x;
  int lg = bid & 127;
  int bsrc = bid >> 7;
  int b = bsrc >> 1, src = bsrc & 1;
  int l0 = lg * 32;
  int tid = threadIdx.x;
  const float* xg = src ? xg1 : xg0;
  const float* gsrc = xg + ((size_t)b * LL + l0) * DI;
  for (int e = tid; e < 32 * 48; e += 192) {
    int row = e / 48, c4 = e % 48;
    *(float4*)&sU[row][c4 * 4] = *(const float4*)(gsrc + (size_t)row * DI + c4 * 4);
  }
  int c = tid >> 2, dseg = tid & 3;
  bool active = (c < C38);
  int cs = active ? c : 0;
  int k0 = src, k1 = src + 2;
  const float4* wp0 = (const float4*)(xpw + ((size_t)k0 * C38 + cs) * DI + dseg * 48);
  const float4* wp1 = (const float4*)(xpw + ((size_t)k1 * C38 + cs) * DI + dseg * 48);
  float4 w0[12], w1[12];
#pragma unroll
  for (int j = 0; j < 12; ++j) { w0[j] = wp0[j]; w1[j] = wp1[j]; }
  float* od0 = xdblT + ((size_t)(b * 4 + k0) * C38 + cs) * LL;
  float* od1 = xdblT + ((size_t)(b * 4 + k1) * C38 + cs) * LL;
  __syncthreads();
  for (int p = 0; p < 32; ++p) {
    float a0 = 0.f, a1 = 0.f;
    const float* ur = &sU[p][dseg * 48];
#pragma unroll
    for (int j = 0; j < 12; ++j) {
      float4 u = *(const float4*)(ur + j * 4);
      a0 = fmaf(u.x, w0[j].x, a0); a1 = fmaf(u.x, w1[j].x, a1);
      a0 = fmaf(u.y, w0[j].y, a0); a1 = fmaf(u.y, w1[j].y, a1);
      a0 = fmaf(u.z, w0[j].z, a0); a1 = fmaf(u.z, w1[j].z, a1);
      a0 = fmaf(u.w, w0[j].w, a0); a1 = fmaf(u.w, w1[j].w, a1);
    }
    a0 += __shfl_xor(a0, 1, 64); a0 += __shfl_xor(a0, 2, 64);
    a1 += __shfl_xor(a1, 1, 64); a1 += __shfl_xor(a1, 2, 64);
    if (dseg == 0 && active) {
      int l = l0 + p;
      od0[l] = a0;
      od1[LL - 1 - l] = a1;
    }
  }
}

// ---------------- 6a. scan phase A: suffix-sum form (fp32)
__global__ __launch_bounds__(512) void k_scanA(const float* __restrict__ xg0,
                                               const float* __restrict__ xg1,
                                               const float* __restrict__ xdblT,
                                               const float* __restrict__ dtw,
                                               const float* __restrict__ dtb,
                                               const float* __restrict__ Alogs,
                                               float* __restrict__ Pbuf,
                                               float* __restrict__ Sbuf) {
  __shared__ float sX[22][PADL];     // rows 0..5 dts, 6..21 B
  __shared__ float sU[32][PADL];
  __shared__ float sDL[32][PADL];    // dl -> exclusive suffix sum R
  __shared__ float sDU[32][PADL];
  __shared__ float sTot[32];
  int blk = blockIdx.x;
  int cb = blk / NC, c = blk % NC;
  int bk = cb / 6, dg2 = cb % 6;
  int b = bk >> 2, k = bk & 3, d0 = dg2 * 32;
  int tid = threadIdx.x, ci = tid >> 4, n = tid & 15, d = d0 + ci;
  int l0 = c * LC;
  const float* xg = (k & 1) ? xg1 : xg0;
  if (tid < 22 * 16) {
    int r = tid >> 4, c4 = tid & 15;
    float4 v = *(const float4*)(xdblT + ((size_t)(bk * C38 + r) * LL + l0 + c4 * 4));
    *(float4*)&sX[r][c4 * 4] = v;
  }
  float wr[6];
#pragma unroll
  for (int r = 0; r < 6; ++r) wr[r] = dtw[(size_t)(k * DI + d) * 6 + r];
  float bias = dtb[k * DI + d];
  float a2 = -__expf(Alogs[(size_t)(k * DI + d) * NS + n]) * LOG2E;
  for (int e = tid; e < LC * 32; e += 512) {
    int l = e >> 5, dd = e & 31;
    int ll = l0 + l;
    int ls = (k & 2) ? (LL - 1 - ll) : ll;
    sU[dd][l] = xg[((size_t)b * LL + ls) * DI + d0 + dd];
  }
  __syncthreads();
#pragma unroll
  for (int j = 0; j < 4; ++j) {
    int l = n + 16 * j;
    float acc = bias;
#pragma unroll
    for (int r = 0; r < 6; ++r) acc = fmaf(sX[r][l], wr[r], acc);
    float dl = softplusf(acc);
    sDL[ci][l] = dl;
    sDU[ci][l] = dl * sU[ci][l];
  }
  __syncthreads();
  {
    int wv = tid >> 6, lane = tid & 63;
#pragma unroll
    for (int q = 0; q < 4; ++q) {
      int r = wv * 4 + q;
      float v = sDL[r][lane];
#pragma unroll
      for (int dlt = 1; dlt < 64; dlt <<= 1) {
        float t = __shfl_up(v, dlt, 64);
        if (lane >= dlt) v += t;
      }
      float tot = __shfl(v, 63, 64);
      sDL[r][lane] = tot - v;
      if (lane == 0) sTot[r] = tot;
    }
  }
  __syncthreads();
  float h0 = 0.f, h1 = 0.f;
#pragma unroll 4
  for (int l4 = 0; l4 < 16; ++l4) {
    float4 R4  = *(const float4*)&sDL[ci][l4 * 4];
    float4 DU4 = *(const float4*)&sDU[ci][l4 * 4];
    float4 B4  = *(const float4*)&sX[6 + n][l4 * 4];
    h0 = fmaf(EXP2F(R4.x * a2), DU4.x * B4.x, h0);
    h1 = fmaf(EXP2F(R4.y * a2), DU4.y * B4.y, h1);
    h0 = fmaf(EXP2F(R4.z * a2), DU4.z * B4.z, h0);
    h1 = fmaf(EXP2F(R4.w * a2), DU4.w * B4.w, h1);
  }
  int gid = ((size_t)bk * DI + d) * NS + n;
  Pbuf[(size_t)c * ST + gid] = EXP2F(a2 * sTot[ci]);
  Sbuf[(size_t)c * ST + gid] = h0 + h1;
}

// ---------------- 6b. scan phase B (in-place: Hbuf aliases Sbuf)
__global__ __launch_bounds__(256) void k_scanB(const float* __restrict__ Pbuf,
                                               const float* __restrict__ Sbuf,
                                               float* __restrict__ Hbuf) {
  int gid = blockIdx.x * 256 + threadIdx.x;
  float h = 0.f;
  for (int c0 = 0; c0 < NC; c0 += 8) {
    float p[8], s[8];
#pragma unroll
    for (int j = 0; j < 8; ++j) {
      p[j] = Pbuf[(size_t)(c0 + j) * ST + gid];
      s[j] = Sbuf[(size_t)(c0 + j) * ST + gid];
    }
#pragma unroll
    for (int j = 0; j < 8; ++j) {
      Hbuf[(size_t)(c0 + j) * ST + gid] = h;
      h = fmaf(h, p[j], s[j]);
    }
  }
}

// ---------------- 6c. scan phase C (fp32 core, fp16 output)
__global__ __launch_bounds__(512) void k_scanC(const float* __restrict__ xg0,
                                               const float* __restrict__ xg1,
                                               const float* __restrict__ xdblT,
                                               const float* __restrict__ dtw,
                                               const float* __restrict__ dtb,
                                               const float* __restrict__ Alogs,
                                               const float* __restrict__ Ds,
                                               const float* __restrict__ Hbuf,
                                               __half* __restrict__ outy) {
  __shared__ float sX[C38][PADL];    // 0..5 dts, 6..21 B, 22..37 C
  __shared__ float sU[32][PADL];
  __shared__ float sDL[32][PADL];
  __shared__ float sDU[32][PADL];
  int blk = blockIdx.x;
  int cb = blk / NC, c = blk % NC;
  int bk = cb / 6, dg2 = cb % 6;
  int b = bk >> 2, k = bk & 3, d0 = dg2 * 32;
  int tid = threadIdx.x, ci = tid >> 4, n = tid & 15, d = d0 + ci;
  int l0 = c * LC;
  const float* xg = (k & 1) ? xg1 : xg0;
  for (int e = tid; e < C38 * 16; e += 512) {
    int r = e >> 4, c4 = e & 15;
    float4 v = *(const float4*)(xdblT + ((size_t)(bk * C38 + r) * LL + l0 + c4 * 4));
    *(float4*)&sX[r][c4 * 4] = v;
  }
  float wr[6];
#pragma unroll
  for (int r = 0; r < 6; ++r) wr[r] = dtw[(size_t)(k * DI + d) * 6 + r];
  float bias = dtb[k * DI + d];
  float a2 = -__expf(Alogs[(size_t)(k * DI + d) * NS + n]) * LOG2E;
  float Dv = Ds[k * DI + d];
  for (int e = tid; e < LC * 32; e += 512) {
    int l = e >> 5, dd = e & 31;
    int ll = l0 + l;
    int ls = (k & 2) ? (LL - 1 - ll) : ll;
    sU[dd][l] = xg[((size_t)b * LL + ls) * DI + d0 + dd];
  }
  __syncthreads();
#pragma unroll
  for (int j = 0; j < 4; ++j) {
    int l = n + 16 * j;
    float acc = bias;
#pragma unroll
    for (int r = 0; r < 6; ++r) acc = fmaf(sX[r][l], wr[r], acc);
    float dl = softplusf(acc);
    sDL[ci][l] = dl;
    sDU[ci][l] = dl * sU[ci][l];
  }
  __syncthreads();
  float h = Hbuf[(size_t)c * ST + ((size_t)bk * DI + d) * NS + n];
  bool k8 = (n & 8) != 0, k4 = (n & 4) != 0, k2 = (n & 2) != 0, k1 = (n & 1) != 0;
  __half* orow = outy + ((size_t)bk * LL + l0) * DI;
  for (int w16 = 0; w16 < 4; ++w16) {
    float acc[16];
#pragma unroll
    for (int q = 0; q < 4; ++q) {
      int l = w16 * 16 + q * 4;
      float4 DL4 = *(const float4*)&sDL[ci][l];
      float4 DU4 = *(const float4*)&sDU[ci][l];
      float4 B4  = *(const float4*)&sX[6 + n][l];
      float4 C4  = *(const float4*)&sX[22 + n][l];
      h = fmaf(h, EXP2F(DL4.x * a2), DU4.x * B4.x); acc[q * 4 + 0] = h * C4.x;
      h = fmaf(h, EXP2F(DL4.y * a2), DU4.y * B4.y); acc[q * 4 + 1] = h * C4.y;
      h = fmaf(h, EXP2F(DL4.z * a2), DU4.z * B4.z); acc[q * 4 + 2] = h * C4.z;
      h = fmaf(h, EXP2F(DL4.w * a2), DU4.w * B4.w); acc[q * 4 + 3] = h * C4.w;
    }
    float b8[8];
#pragma unroll
    for (int t = 0; t < 8; ++t) {
      float lo = acc[t], hi = acc[t + 8];
      float r = __shfl_xor(k8 ? lo : hi, 8, 64);
      b8[t] = (k8 ? hi : lo) + r;
    }
    float b4v[4];
#pragma unroll
    for (int t = 0; t < 4; ++t) {
      float lo = b8[t], hi = b8[t + 4];
      float r = __shfl_xor(k4 ? lo : hi, 4, 64);
      b4v[t] = (k4 ? hi : lo) + r;
    }
    float b2v[2];
#pragma unroll
    for (int t = 0; t < 2; ++t) {
      float lo = b4v[t], hi = b4v[t + 2];
      float r = __shfl_xor(k2 ? lo : hi, 2, 64);
      b2v[t] = (k2 ? hi : lo) + r;
    }
    float lo = b2v[0], hi = b2v[1];
    float r = __shfl_xor(k1 ? lo : hi, 1, 64);
    float y = (k1 ? hi : lo) + r;
    int lw = w16 * 16 + n;
    y = fmaf(sU[ci][lw], Dv, y);
    orow[(size_t)lw * DI + d0 + ci] = __float2half(y);
  }
}

// ---------------- 8. pooled partial sums
__global__ __launch_bounds__(192) void k_pool(const float* __restrict__ xc, float* __restrict__ partial) {
  int blk = blockIdx.x; int b = blk >> 5; int s = blk & 31;
  int d = threadIdx.x;
  const float* p = xc + ((size_t)b * LL + s * 128) * DI + d;
  float acc = 0.f;
#pragma unroll 8
  for (int l = 0; l < 128; ++l) acc += p[(size_t)l * DI];
  partial[(size_t)blk * DI + d] = acc;
}

// ---------------- 9+10. channel prep + scan + catt
__global__ __launch_bounds__(512) void k_ccomb(const float* __restrict__ partial,
                                               const float* __restrict__ cinw,
                                               const float* __restrict__ cinb,
                                               const float* __restrict__ xcw,
                                               const float* __restrict__ dtcw,
                                               const float* __restrict__ dtcb,
                                               const float* __restrict__ Aclogs,
                                               const float* __restrict__ Dsc,
                                               const float* __restrict__ coutw,
                                               const float* __restrict__ coutb,
                                               float* __restrict__ uc, float* __restrict__ dc,
                                               float* __restrict__ Bc, float* __restrict__ Cc,
                                               float* __restrict__ catt) {
  __shared__ float ycs[BSZ][2][4][DI];
  int t = threadIdx.x;
  for (int g = t; g < BSZ * 2 * DI; g += 512) {
    int l = g % DI; int k = (g / DI) & 1; int b = g / (2 * DI);
    int lsrc = k ? (DI - 1 - l) : l;
    float pv = 0.f;
#pragma unroll 8
    for (int s = 0; s < 32; ++s) pv += partial[(size_t)(b * 32 + s) * DI + lsrc];
    pv *= (1.f / 4096.f);
    float u[4];
#pragma unroll
    for (int i = 0; i < 4; ++i) u[i] = fmaf(pv, cinw[i], cinb[i]);
    int pos = (b * 2 + k) * DI + l;
    float db[C38];
#pragma unroll
    for (int c = 0; c < C38; ++c) {
      float s = 0.f;
#pragma unroll
      for (int i = 0; i < 4; ++i) s = fmaf(u[i], xcw[(k * C38 + c) * 4 + i], s);
      db[c] = s;
    }
#pragma unroll
    for (int i = 0; i < 4; ++i) uc[pos * 4 + i] = u[i];
#pragma unroll
    for (int i = 0; i < 4; ++i) {
      float tt = dtcb[k * 4 + i];
#pragma unroll
      for (int r = 0; r < 6; ++r) tt = fmaf(db[r], dtcw[(k * 4 + i) * 6 + r], tt);
      dc[pos * 4 + i] = softplusf(tt);
    }
#pragma unroll
    for (int n = 0; n < NS; ++n) Bc[pos * NS + n] = db[6 + n];
#pragma unroll
    for (int n = 0; n < NS; ++n) Cc[pos * NS + n] = db[22 + n];
  }
  __threadfence_block();
  __syncthreads();
  int chain = t >> 4;
  int n = t & 15;
  int b = chain >> 3; int k = (chain >> 2) & 1; int i = chain & 3;
  float a  = -__expf(Aclogs[(k * 4 + i) * NS + n]);
  float Dv = Dsc[k * 4 + i];
  const float* dp = dc + (size_t)((b * 2 + k) * DI) * 4 + i;
  const float* up = uc + (size_t)((b * 2 + k) * DI) * 4 + i;
  const float* bp = Bc + (size_t)((b * 2 + k) * DI) * NS + n;
  const float* cp = Cc + (size_t)((b * 2 + k) * DI) * NS + n;
  float h = 0.f;
  float qdA[8], quA[8], qbA[8], qcA[8];
  float qdB[8], quB[8], qbB[8], qcB[8];
#pragma unroll
  for (int j = 0; j < 8; ++j) {
    qdA[j] = dp[j * 4]; quA[j] = up[j * 4];
    qbA[j] = bp[j * 16]; qcA[j] = cp[j * 16];
  }
  for (int r = 0; r < 24; r += 2) {
    int lB = (r + 1) * 8;
#pragma unroll
    for (int j = 0; j < 8; ++j) {
      qdB[j] = dp[(lB + j) * 4]; quB[j] = up[(lB + j) * 4];
      qbB[j] = bp[(lB + j) * 16]; qcB[j] = cp[(lB + j) * 16];
    }
#pragma unroll
    for (int j = 0; j < 8; ++j) {
      float dl = qdA[j], ul = quA[j], Bv = qbA[j], Cv = qcA[j];
      h = fmaf(h, __expf(dl * a), dl * ul * Bv);
      float yv = h * Cv;
      yv += __shfl_xor(yv, 1, 64);
      yv += __shfl_xor(yv, 2, 64);
      yv += __shfl_xor(yv, 4, 64);
      yv += __shfl_xor(yv, 8, 64);
      if (n == 0) ycs[b][k][i][r * 8 + j] = yv + ul * Dv;
    }
    if (r + 2 < 24) {
      int lA = (r + 2) * 8;
#pragma unroll
      for (int j = 0; j < 8; ++j) {
        qdA[j] = dp[(lA + j) * 4]; quA[j] = up[(lA + j) * 4];
        qbA[j] = bp[(lA + j) * 16]; qcA[j] = cp[(lA + j) * 16];
      }
    }
#pragma unroll
    for (int j = 0; j < 8; ++j) {
      float dl = qdB[j], ul = quB[j], Bv = qbB[j], Cv = qcB[j];
      h = fmaf(h, __expf(dl * a), dl * ul * Bv);
      float yv = h * Cv;
      yv += __shfl_xor(yv, 1, 64);
      yv += __shfl_xor(yv, 2, 64);
      yv += __shfl_xor(yv, 4, 64);
      yv += __shfl_xor(yv, 8, 64);
      if (n == 0) ycs[b][k][i][(r + 1) * 8 + j] = yv + ul * Dv;
    }
  }
  __syncthreads();
  float cw[4];
#pragma unroll
  for (int q = 0; q < 4; ++q) cw[q] = coutw[q];
  float cb0 = coutb[0];
  for (int e = t; e < BSZ * DI; e += 512) {
    int bb = e / DI, ll = e % DI;
    float s = cb0;
#pragma unroll
    for (int q = 0; q < 4; ++q)
      s = fmaf(ycs[bb][0][q][ll] + ycs[bb][1][q][DI - 1 - ll], cw[q], s);
    catt[bb * DI + ll] = s;
  }
}

// ---------------- 11. final fuse (fp16 outy reads, weight-amortized out-proj)
__global__ __launch_bounds__(512) void k_final(const __half* __restrict__ outy,
                                               const float* __restrict__ xc,
                                               const float* __restrict__ z,
                                               const float* __restrict__ catt,
                                               const float* __restrict__ onw,
                                               const float* __restrict__ onb,
                                               const float* __restrict__ cnw,
                                               const float* __restrict__ cnb,
                                               const float* __restrict__ WoutT,
                                               float* __restrict__ out) {
  __shared__ __align__(16) float sComb[8][DI + 4];
  int w = threadIdx.x >> 6, lane = threadIdx.x & 63;
  int p = blockIdx.x * 8 + w;
  int b = p >> 12, l = p & 4095;
  int lT = ((l & 63) << 6) | (l >> 6);
  size_t base = (size_t)b * KK * LL;
  const __half* r0 = outy + (base + l) * DI;
  const __half* r1 = outy + (base + 2 * LL + (LL - 1 - l)) * DI;
  const __half* r2 = outy + (base + LL + lT) * DI;
  const __half* r3 = outy + (base + 3 * LL + (LL - 1 - lT)) * DI;
  const float* xcr = xc + ((size_t)b * LL + l) * DI;
  const float* zr  = z + ((size_t)b * LL + l) * DI;
  const float* cattr = catt + b * DI;
  float ys[3], xch[3], zv[3];
  float s1 = 0.f, s2 = 0.f, t1 = 0.f, t2 = 0.f;
#pragma unroll
  for (int j = 0; j < 3; ++j) {
    int d = lane + 64 * j;
    float v = __half2float(r0[d]) + __half2float(r1[d])
            + __half2float(r2[d]) + __half2float(r3[d]);
    ys[j] = v; s1 += v; s2 += v * v;
    float xv = xcr[d] * cattr[d];
    xch[j] = xv; t1 += xv; t2 += xv * xv;
    zv[j] = zr[d];
  }
#pragma unroll
  for (int m = 1; m < 64; m <<= 1) {
    s1 += __shfl_xor(s1, m, 64);
    s2 += __shfl_xor(s2, m, 64);
    t1 += __shfl_xor(t1, m, 64);
    t2 += __shfl_xor(t2, m, 64);
  }
  float mu  = s1 * (1.f / DI);
  float var = s2 * (1.f / DI) - mu * mu;
  float rstd = rsqrtf(var + 1e-5f);
  float mu2  = t1 * (1.f / DI);
  float var2 = t2 * (1.f / DI) - mu2 * mu2;
  float rstd2 = rsqrtf(var2 + 1e-5f);
#pragma unroll
  for (int j = 0; j < 3; ++j) {
    int d = lane + 64 * j;
    float yln  = fmaf((ys[j] - mu) * rstd, onw[d], onb[d]);
    float xchn = fmaf((xch[j] - mu2) * rstd2, cnw[d], cnb[d]);
    sComb[w][d] = (yln + xchn) * siluf(zv[j]);
  }
  __syncthreads();
  if (threadIdx.x < DM) {
    int dm = threadIdx.x;
    float acc[8];
#pragma unroll
    for (int p8 = 0; p8 < 8; ++p8) acc[p8] = 0.f;
    for (int t = 0; t < DI; t += 4) {
      float w0 = WoutT[(size_t)(t + 0) * DM + dm];
      float w1 = WoutT[(size_t)(t + 1) * DM + dm];
      float w2 = WoutT[(size_t)(t + 2) * DM + dm];
      float w3 = WoutT[(size_t)(t + 3) * DM + dm];
#pragma unroll
      for (int p8 = 0; p8 < 8; ++p8) {
        float4 cv = *(const float4*)&sComb[p8][t];
        acc[p8] = fmaf(cv.x, w0, acc[p8]);
        acc[p8] = fmaf(cv.y, w1, acc[p8]);
        acc[p8] = fmaf(cv.z, w2, acc[p8]);
        acc[p8] = fmaf(cv.w, w3, acc[p8]);
      }
    }
#pragma unroll
    for (int p8 = 0; p8 < 8; ++p8)
      out[(size_t)(blockIdx.x * 8 + p8) * DM + dm] = acc[p8];
  }
}

extern "C" void kernel_launch(void* const* d_in, const int* in_sizes, int n_in,
                              void* d_out, int out_size, void* d_ws, size_t ws_size,
                              hipStream_t stream) {
  const float* x     = (const float*)d_in[0];
  const int*   xm    = (const int*)  d_in[1];
  const float* Win   = (const float*)d_in[2];
  const float* w3    = (const float*)d_in[3];
  const float* cbia  = (const float*)d_in[4];
  const float* xpw   = (const float*)d_in[5];
  const float* dtw   = (const float*)d_in[6];
  const float* dtb   = (const float*)d_in[7];
  const float* Alogs = (const float*)d_in[8];
  const float* Ds    = (const float*)d_in[9];
  const float* onw   = (const float*)d_in[10];
  const float* onb   = (const float*)d_in[11];
  const float* Wout  = (const float*)d_in[12];
  const float* cinw  = (const float*)d_in[13];
  const float* cinb  = (const float*)d_in[14];
  const float* coutw = (const float*)d_in[15];
  const float* coutb = (const float*)d_in[16];
  const float* xcw   = (const float*)d_in[17];
  const float* Dsc   = (const float*)d_in[18];
  const float* Aclog = (const float*)d_in[19];
  const float* dtcw  = (const float*)d_in[20];
  const float* dtcb  = (const float*)d_in[21];
  const float* cnw   = (const float*)d_in[22];
  const float* cnb   = (const float*)d_in[23];
  float* out = (float*)d_out;

  float* ws = (float*)d_ws;
  size_t o = 0;
  float* xdblT = ws + o; o += (size_t)BSZ * KK * C38 * LL;
  float* oyreg = ws + o; o += (size_t)BSZ * KK * LL * DI / 2;  // outy as fp16 (25 MB)
  float* xc    = ws + o; o += (size_t)BSZ * LL * DI;
  float* z     = ws + o; o += (size_t)BSZ * LL * DI;
  float* xg0   = ws + o; o += (size_t)BSZ * LL * DI;
  float* xg1   = ws + o; o += (size_t)BSZ * LL * DI;
  float* Sbuf  = ws + o; o += (size_t)NC * ST;
  float* partial = ws + o; o += BSZ * 32 * DI;
  float* uc    = ws + o; o += BSZ * 2 * DI * 4;
  float* dc    = ws + o; o += BSZ * 2 * DI * 4;
  float* Bc    = ws + o; o += BSZ * 2 * DI * NS;
  float* Cc    = ws + o; o += BSZ * 2 * DI * NS;
  float* catt  = ws + o; o += BSZ * DI;
  float* WinT  = ws + o; o += 384 * DM;
  float* WoutT = ws + o; o += DM * DI;
  int*   rnk   = (int*)(ws + o); o += BSZ * LL;
  __half* outy = (__half*)oyreg;   // fp16 outy buffer
  float* xh    = oyreg;            // alias: xh dead before k_scanC writes outy
  float* Pbuf  = oyreg;            // alias: Pbuf consumed by k_scanB before k_scanC writes outy
  float* Hbuf  = Sbuf;             // in-place exclusive scan

  int transBlocks = (384 * DM + DM * DI + 255) / 256;
  k_sorttrans<<<BSZ + transBlocks, 256, 0, stream>>>(xm, rnk, Win, Wout, WinT, WoutT);
  k_inproj<<<(BSZ * LL) / PPB, 384, 0, stream>>>(x, WinT, xh, z);
  k_conv  <<<BSZ * LL, 192, 0, stream>>>(xh, w3, cbia, rnk, xc, xg0, xg1);
  k_xdbl  <<<BSZ * 2 * 128, 192, 0, stream>>>(xg0, xg1, xpw, xdblT);
  k_scanA <<<96 * NC, 512, 0, stream>>>(xg0, xg1, xdblT, dtw, dtb, Alogs, Pbuf, Sbuf);
  k_scanB <<<ST / 256, 256, 0, stream>>>(Pbuf, Sbuf, Hbuf);
  k_scanC <<<96 * NC, 512, 0, stream>>>(xg0, xg1, xdblT, dtw, dtb, Alogs, Ds, Hbuf, outy);
  k_pool  <<<BSZ * 32, 192, 0, stream>>>(xc, partial);
  k_ccomb <<<1, 512, 0, stream>>>(partial, cinw, cinb, xcw, dtcw, dtcb, Aclog, Dsc, coutw, coutb, uc, dc, Bc, Cc, catt);
  k_final <<<(BSZ * LL) / 8, 512, 0, stream>>>(outy, xc, z, catt, onw, onb, cnw, cnb, WoutT, out);
}

// Round 14
// 403.242 us; speedup vs baseline: 7.3529x; 1.0528x over previous
//
#include <hip/hip_runtime.h>
#include <hip/hip_fp16.h>
#include <cstdint>

#define BSZ 4
#define LL  4096
#define DM  96
#define DI  192
#define NS  16
#define KK  4
#define C38 38

#define LC  64          // chunk length
#define NC  64          // number of chunks
#define ST  49152       // chains*NS = 3072*16
#define PADL 68         // LDS row stride (16B-aligned, breaks pow2)
#define PADU 196        // xdbl-tile LDS row stride (floats)

#define EXP2F(x) __builtin_amdgcn_exp2f(x)
#define LOG2F(x) __builtin_amdgcn_logf(x)
#define LOG2E 1.44269504f
#define LN2   0.69314718f

__device__ __forceinline__ float softplusf(float x) {
  float t = EXP2F(-fabsf(x) * LOG2E);
  return fmaxf(x, 0.f) + LN2 * LOG2F(1.f + t);
}
__device__ __forceinline__ float siluf(float x) {
  return x / (1.f + EXP2F(-x * LOG2E));
}

// ---------------- 0. region sort (inverse perm rnk) + weight transposes
__global__ __launch_bounds__(256) void k_sorttrans(const int* __restrict__ xm, int* __restrict__ rnk,
                                                   const float* __restrict__ Win,
                                                   const float* __restrict__ Wout,
                                                   float* __restrict__ WinT,
                                                   float* __restrict__ WoutT) {
  if (blockIdx.x < BSZ) {
    __shared__ int cnt[256];
    __shared__ int mloc[LL];
    int b = blockIdx.x, t = threadIdx.x;
    int c0 = 0;
    for (int i = 0; i < 16; ++i) {
      int p = t * 16 + i;
      int m = xm[b * LL + p];
      mloc[p] = m;
      c0 += (m == 0);
    }
    cnt[t] = c0;
    __syncthreads();
    for (int off = 1; off < 256; off <<= 1) {
      int v = (t >= off) ? cnt[t - off] : 0;
      __syncthreads();
      cnt[t] += v;
      __syncthreads();
    }
    int n0 = cnt[255];
    int zb = cnt[t] - c0;
    for (int i = 0; i < 16; ++i) {
      int p = t * 16 + i;
      int r;
      if (mloc[p] == 0) { r = zb; zb++; }
      else              { r = n0 + p - zb; }
      rnk[b * LL + p] = r;
    }
  } else {
    int e = (blockIdx.x - BSZ) * 256 + threadIdx.x;
    if (e < 384 * DM) {
      int t = e / 384, j = e % 384;
      WinT[e] = Win[(size_t)j * DM + t];
    } else {
      int e2 = e - 384 * DM;
      if (e2 < DM * DI) {
        int t = e2 / DM, dm = e2 % DM;
        WoutT[e2] = Wout[(size_t)dm * DI + t];
      }
    }
  }
}

// ---------------- 1. in_proj (b128 LDS reads: 4 t-steps per ds_read)
#define PPB 16
__global__ __launch_bounds__(384) void k_inproj(const float* __restrict__ x,
                                                const float* __restrict__ WinT,
                                                float* __restrict__ xh,
                                                float* __restrict__ z) {
  __shared__ __align__(16) float xv[PPB][DM];
  int j  = threadIdx.x;
  int p0 = blockIdx.x * PPB;
  for (int e = j; e < PPB * DM; e += 384) {
    int pp = e / DM, tt = e % DM;
    xv[pp][tt] = x[(size_t)(p0 + pp) * DM + tt];
  }
  __syncthreads();
  float acc[PPB];
#pragma unroll
  for (int pp = 0; pp < PPB; ++pp) acc[pp] = 0.f;
  for (int t = 0; t < DM; t += 4) {
    float w0 = WinT[(size_t)(t + 0) * 384 + j];
    float w1 = WinT[(size_t)(t + 1) * 384 + j];
    float w2 = WinT[(size_t)(t + 2) * 384 + j];
    float w3 = WinT[(size_t)(t + 3) * 384 + j];
#pragma unroll
    for (int pp = 0; pp < PPB; ++pp) {
      float4 xq = *(const float4*)&xv[pp][t];
      acc[pp] = fmaf(xq.x, w0, acc[pp]);
      acc[pp] = fmaf(xq.y, w1, acc[pp]);
      acc[pp] = fmaf(xq.z, w2, acc[pp]);
      acc[pp] = fmaf(xq.w, w3, acc[pp]);
    }
  }
#pragma unroll
  for (int pp = 0; pp < PPB; ++pp) {
    size_t p = (size_t)(p0 + pp);
    if (j < DI) xh[p * DI + j] = acc[pp];
    else        z[p * DI + (j - DI)] = acc[pp];
  }
}

// ---------------- 2. depthwise 3x3 conv + silu; writes xc + both gathered orders
__global__ __launch_bounds__(192) void k_conv(const float* __restrict__ xh,
                                              const float* __restrict__ w3,
                                              const float* __restrict__ cb,
                                              const int* __restrict__ rnk,
                                              float* __restrict__ xc,
                                              float* __restrict__ xg0,
                                              float* __restrict__ xg1) {
  int p = blockIdx.x; int b = p >> 12; int l = p & 4095;
  int h = l >> 6, w = l & 63;
  int c = threadIdx.x;
  float wr[9];
#pragma unroll
  for (int j = 0; j < 9; ++j) wr[j] = w3[c * 9 + j];
  float acc = cb[c];
#pragma unroll
  for (int kh = 0; kh < 3; ++kh) {
    int hh = h + kh - 1;
    if ((unsigned)hh >= 64u) continue;
#pragma unroll
    for (int kw = 0; kw < 3; ++kw) {
      int ww2 = w + kw - 1;
      if ((unsigned)ww2 >= 64u) continue;
      acc = fmaf(xh[((size_t)b * LL + (hh << 6) + ww2) * DI + c], wr[kh * 3 + kw], acc);
    }
  }
  float v = siluf(acc);
  xc[(size_t)p * DI + c] = v;
  int r = rnk[b * LL + l];
  xg0[((size_t)b * LL + r) * DI + c] = v;
  int lT = ((l & 63) << 6) | (l >> 6);
  xg1[((size_t)b * LL + lT) * DI + c] = v;
}

// ---------------- 5. x_dbl: weight-stationary regs, LDS-broadcast U, 32-row tiles
__global__ __launch_bounds__(192) void k_xdbl(const float* __restrict__ xg0,
                                              const float* __restrict__ xg1,
                                              const float* __restrict__ xpw,
                                              float* __restrict__ xdblT) {
  __shared__ float sU[32][PADU];
  int bid = blockIdx.x;
  int lg = bid & 127;
  int bsrc = bid >> 7;
  int b = bsrc >> 1, src = bsrc & 1;
  int l0 = lg * 32;
  int tid = threadIdx.x;
  const float* xg = src ? xg1 : xg0;
  const float* gsrc = xg + ((size_t)b * LL + l0) * DI;
  for (int e = tid; e < 32 * 48; e += 192) {
    int row = e / 48, c4 = e % 48;
    *(float4*)&sU[row][c4 * 4] = *(const float4*)(gsrc + (size_t)row * DI + c4 * 4);
  }
  int c = tid >> 2, dseg = tid & 3;
  bool active = (c < C38);
  int cs = active ? c : 0;
  int k0 = src, k1 = src + 2;
  const float4* wp0 = (const float4*)(xpw + ((size_t)k0 * C38 + cs) * DI + dseg * 48);
  const float4* wp1 = (const float4*)(xpw + ((size_t)k1 * C38 + cs) * DI + dseg * 48);
  float4 w0[12], w1[12];
#pragma unroll
  for (int j = 0; j < 12; ++j) { w0[j] = wp0[j]; w1[j] = wp1[j]; }
  float* od0 = xdblT + ((size_t)(b * 4 + k0) * C38 + cs) * LL;
  float* od1 = xdblT + ((size_t)(b * 4 + k1) * C38 + cs) * LL;
  __syncthreads();
  for (int p = 0; p < 32; ++p) {
    float a0 = 0.f, a1 = 0.f;
    const float* ur = &sU[p][dseg * 48];
#pragma unroll
    for (int j = 0; j < 12; ++j) {
      float4 u = *(const float4*)(ur + j * 4);
      a0 = fmaf(u.x, w0[j].x, a0); a1 = fmaf(u.x, w1[j].x, a1);
      a0 = fmaf(u.y, w0[j].y, a0); a1 = fmaf(u.y, w1[j].y, a1);
      a0 = fmaf(u.z, w0[j].z, a0); a1 = fmaf(u.z, w1[j].z, a1);
      a0 = fmaf(u.w, w0[j].w, a0); a1 = fmaf(u.w, w1[j].w, a1);
    }
    a0 += __shfl_xor(a0, 1, 64); a0 += __shfl_xor(a0, 2, 64);
    a1 += __shfl_xor(a1, 1, 64); a1 += __shfl_xor(a1, 2, 64);
    if (dseg == 0 && active) {
      int l = l0 + p;
      od0[l] = a0;
      od1[LL - 1 - l] = a1;
    }
  }
}

// ---------------- 6a. scan phase A: serial aggregate (no prefix scan)
__global__ __launch_bounds__(512) void k_scanA(const float* __restrict__ xg0,
                                               const float* __restrict__ xg1,
                                               const float* __restrict__ xdblT,
                                               const float* __restrict__ dtw,
                                               const float* __restrict__ dtb,
                                               const float* __restrict__ Alogs,
                                               float* __restrict__ Pbuf,
                                               float* __restrict__ Sbuf) {
  __shared__ float sX[22][PADL];     // rows 0..5 dts, 6..21 B
  __shared__ float sU[32][PADL];
  __shared__ float sDL[32][PADL];
  __shared__ float sDU[32][PADL];
  int blk = blockIdx.x;
  int cb = blk / NC, c = blk % NC;
  int bk = cb / 6, dg2 = cb % 6;
  int b = bk >> 2, k = bk & 3, d0 = dg2 * 32;
  int tid = threadIdx.x, ci = tid >> 4, n = tid & 15, d = d0 + ci;
  int l0 = c * LC;
  const float* xg = (k & 1) ? xg1 : xg0;
  if (tid < 22 * 16) {
    int r = tid >> 4, c4 = tid & 15;
    float4 v = *(const float4*)(xdblT + ((size_t)(bk * C38 + r) * LL + l0 + c4 * 4));
    *(float4*)&sX[r][c4 * 4] = v;
  }
  float wr[6];
#pragma unroll
  for (int r = 0; r < 6; ++r) wr[r] = dtw[(size_t)(k * DI + d) * 6 + r];
  float bias = dtb[k * DI + d];
  float a2 = -__expf(Alogs[(size_t)(k * DI + d) * NS + n]) * LOG2E;
  for (int e = tid; e < LC * 32; e += 512) {
    int l = e >> 5, dd = e & 31;
    int ll = l0 + l;
    int ls = (k & 2) ? (LL - 1 - ll) : ll;
    sU[dd][l] = xg[((size_t)b * LL + ls) * DI + d0 + dd];
  }
  __syncthreads();
  float tsum = 0.f;
#pragma unroll
  for (int j = 0; j < 4; ++j) {
    int l = n + 16 * j;
    float acc = bias;
#pragma unroll
    for (int r = 0; r < 6; ++r) acc = fmaf(sX[r][l], wr[r], acc);
    float dl = softplusf(acc);
    sDL[ci][l] = dl;
    sDU[ci][l] = dl * sU[ci][l];
    tsum += dl;
  }
  // sum dl over the 16 n-lanes of this d-row -> P
  tsum += __shfl_xor(tsum, 1, 64);
  tsum += __shfl_xor(tsum, 2, 64);
  tsum += __shfl_xor(tsum, 4, 64);
  tsum += __shfl_xor(tsum, 8, 64);
  float Pv = EXP2F(a2 * tsum);
  __syncthreads();
  // serial chunk-local state from 0
  float S = 0.f;
#pragma unroll 4
  for (int l4 = 0; l4 < 16; ++l4) {
    float4 DL4 = *(const float4*)&sDL[ci][l4 * 4];
    float4 DU4 = *(const float4*)&sDU[ci][l4 * 4];
    float4 B4  = *(const float4*)&sX[6 + n][l4 * 4];
    S = fmaf(S, EXP2F(DL4.x * a2), DU4.x * B4.x);
    S = fmaf(S, EXP2F(DL4.y * a2), DU4.y * B4.y);
    S = fmaf(S, EXP2F(DL4.z * a2), DU4.z * B4.z);
    S = fmaf(S, EXP2F(DL4.w * a2), DU4.w * B4.w);
  }
  int gid = ((size_t)bk * DI + d) * NS + n;
  Pbuf[(size_t)c * ST + gid] = Pv;
  Sbuf[(size_t)c * ST + gid] = S;
}

// ---------------- 6b. scan phase B (in-place) + pooled partial sums (extra blocks)
__global__ __launch_bounds__(256) void k_scanB(const float* __restrict__ Pbuf,
                                               const float* __restrict__ Sbuf,
                                               float* __restrict__ Hbuf,
                                               const float* __restrict__ xc,
                                               float* __restrict__ partial) {
  if (blockIdx.x < ST / 256) {
    int gid = blockIdx.x * 256 + threadIdx.x;
    float h = 0.f;
    for (int c0 = 0; c0 < NC; c0 += 8) {
      float p[8], s[8];
#pragma unroll
      for (int j = 0; j < 8; ++j) {
        p[j] = Pbuf[(size_t)(c0 + j) * ST + gid];
        s[j] = Sbuf[(size_t)(c0 + j) * ST + gid];
      }
#pragma unroll
      for (int j = 0; j < 8; ++j) {
        Hbuf[(size_t)(c0 + j) * ST + gid] = h;
        h = fmaf(h, p[j], s[j]);
      }
    }
  } else {
    int blk = blockIdx.x - ST / 256;   // 0..127
    int b = blk >> 5; int s = blk & 31;
    int d = threadIdx.x;
    if (d < DI) {
      const float* p = xc + ((size_t)b * LL + s * 128) * DI + d;
      float acc = 0.f;
#pragma unroll 8
      for (int l = 0; l < 128; ++l) acc += p[(size_t)l * DI];
      partial[(size_t)blk * DI + d] = acc;
    }
  }
}

// ---------------- 6c. scan phase C (fp32 core, fp16 output)
__global__ __launch_bounds__(512) void k_scanC(const float* __restrict__ xg0,
                                               const float* __restrict__ xg1,
                                               const float* __restrict__ xdblT,
                                               const float* __restrict__ dtw,
                                               const float* __restrict__ dtb,
                                               const float* __restrict__ Alogs,
                                               const float* __restrict__ Ds,
                                               const float* __restrict__ Hbuf,
                                               __half* __restrict__ outy) {
  __shared__ float sX[C38][PADL];    // 0..5 dts, 6..21 B, 22..37 C
  __shared__ float sU[32][PADL];
  __shared__ float sDL[32][PADL];
  __shared__ float sDU[32][PADL];
  int blk = blockIdx.x;
  int cb = blk / NC, c = blk % NC;
  int bk = cb / 6, dg2 = cb % 6;
  int b = bk >> 2, k = bk & 3, d0 = dg2 * 32;
  int tid = threadIdx.x, ci = tid >> 4, n = tid & 15, d = d0 + ci;
  int l0 = c * LC;
  const float* xg = (k & 1) ? xg1 : xg0;
  for (int e = tid; e < C38 * 16; e += 512) {
    int r = e >> 4, c4 = e & 15;
    float4 v = *(const float4*)(xdblT + ((size_t)(bk * C38 + r) * LL + l0 + c4 * 4));
    *(float4*)&sX[r][c4 * 4] = v;
  }
  float wr[6];
#pragma unroll
  for (int r = 0; r < 6; ++r) wr[r] = dtw[(size_t)(k * DI + d) * 6 + r];
  float bias = dtb[k * DI + d];
  float a2 = -__expf(Alogs[(size_t)(k * DI + d) * NS + n]) * LOG2E;
  float Dv = Ds[k * DI + d];
  for (int e = tid; e < LC * 32; e += 512) {
    int l = e >> 5, dd = e & 31;
    int ll = l0 + l;
    int ls = (k & 2) ? (LL - 1 - ll) : ll;
    sU[dd][l] = xg[((size_t)b * LL + ls) * DI + d0 + dd];
  }
  __syncthreads();
#pragma unroll
  for (int j = 0; j < 4; ++j) {
    int l = n + 16 * j;
    float acc = bias;
#pragma unroll
    for (int r = 0; r < 6; ++r) acc = fmaf(sX[r][l], wr[r], acc);
    float dl = softplusf(acc);
    sDL[ci][l] = dl;
    sDU[ci][l] = dl * sU[ci][l];
  }
  __syncthreads();
  float h = Hbuf[(size_t)c * ST + ((size_t)bk * DI + d) * NS + n];
  bool k8 = (n & 8) != 0, k4 = (n & 4) != 0, k2 = (n & 2) != 0, k1 = (n & 1) != 0;
  __half* orow = outy + ((size_t)bk * LL + l0) * DI;
  for (int w16 = 0; w16 < 4; ++w16) {
    float acc[16];
#pragma unroll
    for (int q = 0; q < 4; ++q) {
      int l = w16 * 16 + q * 4;
      float4 DL4 = *(const float4*)&sDL[ci][l];
      float4 DU4 = *(const float4*)&sDU[ci][l];
      float4 B4  = *(const float4*)&sX[6 + n][l];
      float4 C4  = *(const float4*)&sX[22 + n][l];
      h = fmaf(h, EXP2F(DL4.x * a2), DU4.x * B4.x); acc[q * 4 + 0] = h * C4.x;
      h = fmaf(h, EXP2F(DL4.y * a2), DU4.y * B4.y); acc[q * 4 + 1] = h * C4.y;
      h = fmaf(h, EXP2F(DL4.z * a2), DU4.z * B4.z); acc[q * 4 + 2] = h * C4.z;
      h = fmaf(h, EXP2F(DL4.w * a2), DU4.w * B4.w); acc[q * 4 + 3] = h * C4.w;
    }
    float b8[8];
#pragma unroll
    for (int t = 0; t < 8; ++t) {
      float lo = acc[t], hi = acc[t + 8];
      float r = __shfl_xor(k8 ? lo : hi, 8, 64);
      b8[t] = (k8 ? hi : lo) + r;
    }
    float b4v[4];
#pragma unroll
    for (int t = 0; t < 4; ++t) {
      float lo = b8[t], hi = b8[t + 4];
      float r = __shfl_xor(k4 ? lo : hi, 4, 64);
      b4v[t] = (k4 ? hi : lo) + r;
    }
    float b2v[2];
#pragma unroll
    for (int t = 0; t < 2; ++t) {
      float lo = b4v[t], hi = b4v[t + 2];
      float r = __shfl_xor(k2 ? lo : hi, 2, 64);
      b2v[t] = (k2 ? hi : lo) + r;
    }
    float lo = b2v[0], hi = b2v[1];
    float r = __shfl_xor(k1 ? lo : hi, 1, 64);
    float y = (k1 ? hi : lo) + r;
    int lw = w16 * 16 + n;
    y = fmaf(sU[ci][lw], Dv, y);
    orow[(size_t)lw * DI + d0 + ci] = __float2half(y);
  }
}

// ---------------- 9+10. channel prep + scan + catt
__global__ __launch_bounds__(512) void k_ccomb(const float* __restrict__ partial,
                                               const float* __restrict__ cinw,
                                               const float* __restrict__ cinb,
                                               const float* __restrict__ xcw,
                                               const float* __restrict__ dtcw,
                                               const float* __restrict__ dtcb,
                                               const float* __restrict__ Aclogs,
                                               const float* __restrict__ Dsc,
                                               const float* __restrict__ coutw,
                                               const float* __restrict__ coutb,
                                               float* __restrict__ uc, float* __restrict__ dc,
                                               float* __restrict__ Bc, float* __restrict__ Cc,
                                               float* __restrict__ catt) {
  __shared__ float ycs[BSZ][2][4][DI];
  int t = threadIdx.x;
  for (int g = t; g < BSZ * 2 * DI; g += 512) {
    int l = g % DI; int k = (g / DI) & 1; int b = g / (2 * DI);
    int lsrc = k ? (DI - 1 - l) : l;
    float pv = 0.f;
#pragma unroll 8
    for (int s = 0; s < 32; ++s) pv += partial[(size_t)(b * 32 + s) * DI + lsrc];
    pv *= (1.f / 4096.f);
    float u[4];
#pragma unroll
    for (int i = 0; i < 4; ++i) u[i] = fmaf(pv, cinw[i], cinb[i]);
    int pos = (b * 2 + k) * DI + l;
    float db[C38];
#pragma unroll
    for (int c = 0; c < C38; ++c) {
      float s = 0.f;
#pragma unroll
      for (int i = 0; i < 4; ++i) s = fmaf(u[i], xcw[(k * C38 + c) * 4 + i], s);
      db[c] = s;
    }
#pragma unroll
    for (int i = 0; i < 4; ++i) uc[pos * 4 + i] = u[i];
#pragma unroll
    for (int i = 0; i < 4; ++i) {
      float tt = dtcb[k * 4 + i];
#pragma unroll
      for (int r = 0; r < 6; ++r) tt = fmaf(db[r], dtcw[(k * 4 + i) * 6 + r], tt);
      dc[pos * 4 + i] = softplusf(tt);
    }
#pragma unroll
    for (int n = 0; n < NS; ++n) Bc[pos * NS + n] = db[6 + n];
#pragma unroll
    for (int n = 0; n < NS; ++n) Cc[pos * NS + n] = db[22 + n];
  }
  __threadfence_block();
  __syncthreads();
  int chain = t >> 4;
  int n = t & 15;
  int b = chain >> 3; int k = (chain >> 2) & 1; int i = chain & 3;
  float a  = -__expf(Aclogs[(k * 4 + i) * NS + n]);
  float Dv = Dsc[k * 4 + i];
  const float* dp = dc + (size_t)((b * 2 + k) * DI) * 4 + i;
  const float* up = uc + (size_t)((b * 2 + k) * DI) * 4 + i;
  const float* bp = Bc + (size_t)((b * 2 + k) * DI) * NS + n;
  const float* cp = Cc + (size_t)((b * 2 + k) * DI) * NS + n;
  float h = 0.f;
  float qdA[8], quA[8], qbA[8], qcA[8];
  float qdB[8], quB[8], qbB[8], qcB[8];
#pragma unroll
  for (int j = 0; j < 8; ++j) {
    qdA[j] = dp[j * 4]; quA[j] = up[j * 4];
    qbA[j] = bp[j * 16]; qcA[j] = cp[j * 16];
  }
  for (int r = 0; r < 24; r += 2) {
    int lB = (r + 1) * 8;
#pragma unroll
    for (int j = 0; j < 8; ++j) {
      qdB[j] = dp[(lB + j) * 4]; quB[j] = up[(lB + j) * 4];
      qbB[j] = bp[(lB + j) * 16]; qcB[j] = cp[(lB + j) * 16];
    }
#pragma unroll
    for (int j = 0; j < 8; ++j) {
      float dl = qdA[j], ul = quA[j], Bv = qbA[j], Cv = qcA[j];
      h = fmaf(h, __expf(dl * a), dl * ul * Bv);
      float yv = h * Cv;
      yv += __shfl_xor(yv, 1, 64);
      yv += __shfl_xor(yv, 2, 64);
      yv += __shfl_xor(yv, 4, 64);
      yv += __shfl_xor(yv, 8, 64);
      if (n == 0) ycs[b][k][i][r * 8 + j] = yv + ul * Dv;
    }
    if (r + 2 < 24) {
      int lA = (r + 2) * 8;
#pragma unroll
      for (int j = 0; j < 8; ++j) {
        qdA[j] = dp[(lA + j) * 4]; quA[j] = up[(lA + j) * 4];
        qbA[j] = bp[(lA + j) * 16]; qcA[j] = cp[(lA + j) * 16];
      }
    }
#pragma unroll
    for (int j = 0; j < 8; ++j) {
      float dl = qdB[j], ul = quB[j], Bv = qbB[j], Cv = qcB[j];
      h = fmaf(h, __expf(dl * a), dl * ul * Bv);
      float yv = h * Cv;
      yv += __shfl_xor(yv, 1, 64);
      yv += __shfl_xor(yv, 2, 64);
      yv += __shfl_xor(yv, 4, 64);
      yv += __shfl_xor(yv, 8, 64);
      if (n == 0) ycs[b][k][i][(r + 1) * 8 + j] = yv + ul * Dv;
    }
  }
  __syncthreads();
  float cw[4];
#pragma unroll
  for (int q = 0; q < 4; ++q) cw[q] = coutw[q];
  float cb0 = coutb[0];
  for (int e = t; e < BSZ * DI; e += 512) {
    int bb = e / DI, ll = e % DI;
    float s = cb0;
#pragma unroll
    for (int q = 0; q < 4; ++q)
      s = fmaf(ycs[bb][0][q][ll] + ycs[bb][1][q][DI - 1 - ll], cw[q], s);
    catt[bb * DI + ll] = s;
  }
}

// ---------------- 11. final fuse (fp16 outy reads, weight-amortized out-proj)
__global__ __launch_bounds__(512) void k_final(const __half* __restrict__ outy,
                                               const float* __restrict__ xc,
                                               const float* __restrict__ z,
                                               const float* __restrict__ catt,
                                               const float* __restrict__ onw,
                                               const float* __restrict__ onb,
                                               const float* __restrict__ cnw,
                                               const float* __restrict__ cnb,
                                               const float* __restrict__ WoutT,
                                               float* __restrict__ out) {
  __shared__ __align__(16) float sComb[8][DI + 4];
  int w = threadIdx.x >> 6, lane = threadIdx.x & 63;
  int p = blockIdx.x * 8 + w;
  int b = p >> 12, l = p & 4095;
  int lT = ((l & 63) << 6) | (l >> 6);
  size_t base = (size_t)b * KK * LL;
  const __half* r0 = outy + (base + l) * DI;
  const __half* r1 = outy + (base + 2 * LL + (LL - 1 - l)) * DI;
  const __half* r2 = outy + (base + LL + lT) * DI;
  const __half* r3 = outy + (base + 3 * LL + (LL - 1 - lT)) * DI;
  const float* xcr = xc + ((size_t)b * LL + l) * DI;
  const float* zr  = z + ((size_t)b * LL + l) * DI;
  const float* cattr = catt + b * DI;
  float ys[3], xch[3], zv[3];
  float s1 = 0.f, s2 = 0.f, t1 = 0.f, t2 = 0.f;
#pragma unroll
  for (int j = 0; j < 3; ++j) {
    int d = lane + 64 * j;
    float v = __half2float(r0[d]) + __half2float(r1[d])
            + __half2float(r2[d]) + __half2float(r3[d]);
    ys[j] = v; s1 += v; s2 += v * v;
    float xv = xcr[d] * cattr[d];
    xch[j] = xv; t1 += xv; t2 += xv * xv;
    zv[j] = zr[d];
  }
#pragma unroll
  for (int m = 1; m < 64; m <<= 1) {
    s1 += __shfl_xor(s1, m, 64);
    s2 += __shfl_xor(s2, m, 64);
    t1 += __shfl_xor(t1, m, 64);
    t2 += __shfl_xor(t2, m, 64);
  }
  float mu  = s1 * (1.f / DI);
  float var = s2 * (1.f / DI) - mu * mu;
  float rstd = rsqrtf(var + 1e-5f);
  float mu2  = t1 * (1.f / DI);
  float var2 = t2 * (1.f / DI) - mu2 * mu2;
  float rstd2 = rsqrtf(var2 + 1e-5f);
#pragma unroll
  for (int j = 0; j < 3; ++j) {
    int d = lane + 64 * j;
    float yln  = fmaf((ys[j] - mu) * rstd, onw[d], onb[d]);
    float xchn = fmaf((xch[j] - mu2) * rstd2, cnw[d], cnb[d]);
    sComb[w][d] = (yln + xchn) * siluf(zv[j]);
  }
  __syncthreads();
  if (threadIdx.x < DM) {
    int dm = threadIdx.x;
    float acc[8];
#pragma unroll
    for (int p8 = 0; p8 < 8; ++p8) acc[p8] = 0.f;
    for (int t = 0; t < DI; t += 4) {
      float w0 = WoutT[(size_t)(t + 0) * DM + dm];
      float w1 = WoutT[(size_t)(t + 1) * DM + dm];
      float w2 = WoutT[(size_t)(t + 2) * DM + dm];
      float w3 = WoutT[(size_t)(t + 3) * DM + dm];
#pragma unroll
      for (int p8 = 0; p8 < 8; ++p8) {
        float4 cv = *(const float4*)&sComb[p8][t];
        acc[p8] = fmaf(cv.x, w0, acc[p8]);
        acc[p8] = fmaf(cv.y, w1, acc[p8]);
        acc[p8] = fmaf(cv.z, w2, acc[p8]);
        acc[p8] = fmaf(cv.w, w3, acc[p8]);
      }
    }
#pragma unroll
    for (int p8 = 0; p8 < 8; ++p8)
      out[(size_t)(blockIdx.x * 8 + p8) * DM + dm] = acc[p8];
  }
}

extern "C" void kernel_launch(void* const* d_in, const int* in_sizes, int n_in,
                              void* d_out, int out_size, void* d_ws, size_t ws_size,
                              hipStream_t stream) {
  const float* x     = (const float*)d_in[0];
  const int*   xm    = (const int*)  d_in[1];
  const float* Win   = (const float*)d_in[2];
  const float* w3    = (const float*)d_in[3];
  const float* cbia  = (const float*)d_in[4];
  const float* xpw   = (const float*)d_in[5];
  const float* dtw   = (const float*)d_in[6];
  const float* dtb   = (const float*)d_in[7];
  const float* Alogs = (const float*)d_in[8];
  const float* Ds    = (const float*)d_in[9];
  const float* onw   = (const float*)d_in[10];
  const float* onb   = (const float*)d_in[11];
  const float* Wout  = (const float*)d_in[12];
  const float* cinw  = (const float*)d_in[13];
  const float* cinb  = (const float*)d_in[14];
  const float* coutw = (const float*)d_in[15];
  const float* coutb = (const float*)d_in[16];
  const float* xcw   = (const float*)d_in[17];
  const float* Dsc   = (const float*)d_in[18];
  const float* Aclog = (const float*)d_in[19];
  const float* dtcw  = (const float*)d_in[20];
  const float* dtcb  = (const float*)d_in[21];
  const float* cnw   = (const float*)d_in[22];
  const float* cnb   = (const float*)d_in[23];
  float* out = (float*)d_out;

  float* ws = (float*)d_ws;
  size_t o = 0;
  float* xdblT = ws + o; o += (size_t)BSZ * KK * C38 * LL;
  float* oyreg = ws + o; o += (size_t)BSZ * KK * LL * DI / 2;  // outy as fp16 (25 MB)
  float* xc    = ws + o; o += (size_t)BSZ * LL * DI;
  float* z     = ws + o; o += (size_t)BSZ * LL * DI;
  float* xg0   = ws + o; o += (size_t)BSZ * LL * DI;
  float* xg1   = ws + o; o += (size_t)BSZ * LL * DI;
  float* Sbuf  = ws + o; o += (size_t)NC * ST;
  float* partial = ws + o; o += BSZ * 32 * DI;
  float* uc    = ws + o; o += BSZ * 2 * DI * 4;
  float* dc    = ws + o; o += BSZ * 2 * DI * 4;
  float* Bc    = ws + o; o += BSZ * 2 * DI * NS;
  float* Cc    = ws + o; o += BSZ * 2 * DI * NS;
  float* catt  = ws + o; o += BSZ * DI;
  float* WinT  = ws + o; o += 384 * DM;
  float* WoutT = ws + o; o += DM * DI;
  int*   rnk   = (int*)(ws + o); o += BSZ * LL;
  __half* outy = (__half*)oyreg;   // fp16 outy buffer
  float* xh    = oyreg;            // alias: xh dead before k_scanC writes outy
  float* Pbuf  = oyreg;            // alias: Pbuf consumed by k_scanB before k_scanC writes outy
  float* Hbuf  = Sbuf;             // in-place exclusive scan

  int transBlocks = (384 * DM + DM * DI + 255) / 256;
  k_sorttrans<<<BSZ + transBlocks, 256, 0, stream>>>(xm, rnk, Win, Wout, WinT, WoutT);
  k_inproj<<<(BSZ * LL) / PPB, 384, 0, stream>>>(x, WinT, xh, z);
  k_conv  <<<BSZ * LL, 192, 0, stream>>>(xh, w3, cbia, rnk, xc, xg0, xg1);
  k_xdbl  <<<BSZ * 2 * 128, 192, 0, stream>>>(xg0, xg1, xpw, xdblT);
  k_scanA <<<96 * NC, 512, 0, stream>>>(xg0, xg1, xdblT, dtw, dtb, Alogs, Pbuf, Sbuf);
  k_scanB <<<ST / 256 + BSZ * 32, 256, 0, stream>>>(Pbuf, Sbuf, Hbuf, xc, partial);
  k_scanC <<<96 * NC, 512, 0, stream>>>(xg0, xg1, xdblT, dtw, dtb, Alogs, Ds, Hbuf, outy);
  k_ccomb <<<1, 512, 0, stream>>>(partial, cinw, cinb, xcw, dtcw, dtcb, Aclog, Dsc, coutw, coutb, uc, dc, Bc, Cc, catt);
  k_final <<<(BSZ * LL) / 8, 512, 0, stream>>>(outy, xc, z, catt, onw, onb, cnw, cnb, WoutT, out);
}

// Round 15
// 402.827 us; speedup vs baseline: 7.3604x; 1.0010x over previous
//
#include <hip/hip_runtime.h>
#include <hip/hip_fp16.h>
#include <cstdint>

#define BSZ 4
#define LL  4096
#define DM  96
#define DI  192
#define NS  16
#define KK  4
#define C38 38

#define LC  64          // chunk length
#define NC  64          // number of chunks
#define ST  49152       // chains*NS = 3072*16
#define PADL 68         // LDS row stride (16B-aligned, breaks pow2)

#define EXP2F(x) __builtin_amdgcn_exp2f(x)
#define LOG2F(x) __builtin_amdgcn_logf(x)
#define LOG2E 1.44269504f
#define LN2   0.69314718f

typedef _Float16 h2_t __attribute__((ext_vector_type(2)));

#if __has_builtin(__builtin_amdgcn_fdot2)
#define FDOT2(a, b, c) __builtin_amdgcn_fdot2(*(h2_t*)&(a), *(h2_t*)&(b), (c), false)
#else
static __device__ __forceinline__ float _fdot2_fb(unsigned ua, unsigned ub, float c) {
  float2 fa = __half22float2(*(__half2*)&ua);
  float2 fb = __half22float2(*(__half2*)&ub);
  return fmaf(fa.y, fb.y, fmaf(fa.x, fb.x, c));
}
#define FDOT2(a, b, c) _fdot2_fb((a), (b), (c))
#endif

__device__ __forceinline__ float softplusf(float x) {
  float t = EXP2F(-fabsf(x) * LOG2E);
  return fmaxf(x, 0.f) + LN2 * LOG2F(1.f + t);
}
__device__ __forceinline__ float siluf(float x) {
  return x / (1.f + EXP2F(-x * LOG2E));
}

// ---------------- 0. region sort (inverse perm rnk) + weight transposes
__global__ __launch_bounds__(256) void k_sorttrans(const int* __restrict__ xm, int* __restrict__ rnk,
                                                   const float* __restrict__ Win,
                                                   const float* __restrict__ Wout,
                                                   float* __restrict__ WinT,
                                                   float* __restrict__ WoutT) {
  if (blockIdx.x < BSZ) {
    __shared__ int cnt[256];
    __shared__ int mloc[LL];
    int b = blockIdx.x, t = threadIdx.x;
    int c0 = 0;
    for (int i = 0; i < 16; ++i) {
      int p = t * 16 + i;
      int m = xm[b * LL + p];
      mloc[p] = m;
      c0 += (m == 0);
    }
    cnt[t] = c0;
    __syncthreads();
    for (int off = 1; off < 256; off <<= 1) {
      int v = (t >= off) ? cnt[t - off] : 0;
      __syncthreads();
      cnt[t] += v;
      __syncthreads();
    }
    int n0 = cnt[255];
    int zb = cnt[t] - c0;
    for (int i = 0; i < 16; ++i) {
      int p = t * 16 + i;
      int r;
      if (mloc[p] == 0) { r = zb; zb++; }
      else              { r = n0 + p - zb; }
      rnk[b * LL + p] = r;
    }
  } else {
    int e = (blockIdx.x - BSZ) * 256 + threadIdx.x;
    if (e < 384 * DM) {
      int t = e / 384, j = e % 384;
      WinT[e] = Win[(size_t)j * DM + t];
    } else {
      int e2 = e - 384 * DM;
      if (e2 < DM * DI) {
        int t = e2 / DM, dm = e2 % DM;
        WoutT[e2] = Wout[(size_t)dm * DI + t];
      }
    }
  }
}

// ---------------- 1. in_proj (b128 LDS reads), z stored fp16
#define PPB 16
__global__ __launch_bounds__(384) void k_inproj(const float* __restrict__ x,
                                                const float* __restrict__ WinT,
                                                float* __restrict__ xh,
                                                __half* __restrict__ z) {
  __shared__ __align__(16) float xv[PPB][DM];
  int j  = threadIdx.x;
  int p0 = blockIdx.x * PPB;
  for (int e = j; e < PPB * DM; e += 384) {
    int pp = e / DM, tt = e % DM;
    xv[pp][tt] = x[(size_t)(p0 + pp) * DM + tt];
  }
  __syncthreads();
  float acc[PPB];
#pragma unroll
  for (int pp = 0; pp < PPB; ++pp) acc[pp] = 0.f;
  for (int t = 0; t < DM; t += 4) {
    float w0 = WinT[(size_t)(t + 0) * 384 + j];
    float w1 = WinT[(size_t)(t + 1) * 384 + j];
    float w2 = WinT[(size_t)(t + 2) * 384 + j];
    float w3 = WinT[(size_t)(t + 3) * 384 + j];
#pragma unroll
    for (int pp = 0; pp < PPB; ++pp) {
      float4 xq = *(const float4*)&xv[pp][t];
      acc[pp] = fmaf(xq.x, w0, acc[pp]);
      acc[pp] = fmaf(xq.y, w1, acc[pp]);
      acc[pp] = fmaf(xq.z, w2, acc[pp]);
      acc[pp] = fmaf(xq.w, w3, acc[pp]);
    }
  }
#pragma unroll
  for (int pp = 0; pp < PPB; ++pp) {
    size_t p = (size_t)(p0 + pp);
    if (j < DI) xh[p * DI + j] = acc[pp];
    else        z[p * DI + (j - DI)] = __float2half(acc[pp]);
  }
}

// ---------------- 2. depthwise 3x3 conv + silu; xc fp32, xg0/xg1 fp16
__global__ __launch_bounds__(192) void k_conv(const float* __restrict__ xh,
                                              const float* __restrict__ w3,
                                              const float* __restrict__ cb,
                                              const int* __restrict__ rnk,
                                              float* __restrict__ xc,
                                              __half* __restrict__ xg0,
                                              __half* __restrict__ xg1) {
  int p = blockIdx.x; int b = p >> 12; int l = p & 4095;
  int h = l >> 6, w = l & 63;
  int c = threadIdx.x;
  float wr[9];
#pragma unroll
  for (int j = 0; j < 9; ++j) wr[j] = w3[c * 9 + j];
  float acc = cb[c];
#pragma unroll
  for (int kh = 0; kh < 3; ++kh) {
    int hh = h + kh - 1;
    if ((unsigned)hh >= 64u) continue;
#pragma unroll
    for (int kw = 0; kw < 3; ++kw) {
      int ww2 = w + kw - 1;
      if ((unsigned)ww2 >= 64u) continue;
      acc = fmaf(xh[((size_t)b * LL + (hh << 6) + ww2) * DI + c], wr[kh * 3 + kw], acc);
    }
  }
  float v = siluf(acc);
  xc[(size_t)p * DI + c] = v;
  __half vh = __float2half(v);
  int r = rnk[b * LL + l];
  xg0[((size_t)b * LL + r) * DI + c] = vh;
  int lT = ((l & 63) << 6) | (l >> 6);
  xg1[((size_t)b * LL + lT) * DI + c] = vh;
}

// ---------------- 5. x_dbl v5: fp16 LDS tile + dot2, weight-stationary half2 regs
__global__ __launch_bounds__(192) void k_xdbl(const __half* __restrict__ xg0,
                                              const __half* __restrict__ xg1,
                                              const float* __restrict__ xpw,
                                              float* __restrict__ xdblT) {
  __shared__ unsigned sU[32][100];   // 32 rows x 96 half2 (+pad)
  int bid = blockIdx.x;
  int lg = bid & 127;
  int bsrc = bid >> 7;
  int b = bsrc >> 1, src = bsrc & 1;
  int l0 = lg * 32;
  int tid = threadIdx.x;
  const __half* xg = src ? xg1 : xg0;
  const __half* gsrc = xg + ((size_t)b * LL + l0) * DI;
  for (int e = tid; e < 32 * 24; e += 192) {
    int row = e / 24, q = e % 24;
    *(uint4*)&sU[row][q * 4] = *(const uint4*)((const unsigned*)(gsrc + (size_t)row * DI) + q * 4);
  }
  int c = tid >> 2, dseg = tid & 3;
  bool active = (c < C38);
  int cs = active ? c : 0;
  int k0 = src, k1 = src + 2;
  const float* wp0 = xpw + ((size_t)k0 * C38 + cs) * DI + dseg * 48;
  const float* wp1 = xpw + ((size_t)k1 * C38 + cs) * DI + dseg * 48;
  unsigned w0h[24], w1h[24];
#pragma unroll
  for (int j = 0; j < 24; ++j) {
    __half2 h0 = __floats2half2_rn(wp0[j * 2], wp0[j * 2 + 1]);
    __half2 h1 = __floats2half2_rn(wp1[j * 2], wp1[j * 2 + 1]);
    w0h[j] = *(unsigned*)&h0;
    w1h[j] = *(unsigned*)&h1;
  }
  float* od0 = xdblT + ((size_t)(b * 4 + k0) * C38 + cs) * LL;
  float* od1 = xdblT + ((size_t)(b * 4 + k1) * C38 + cs) * LL;
  __syncthreads();
  for (int p = 0; p < 32; ++p) {
    float a0 = 0.f, a1 = 0.f;
    const unsigned* ur = &sU[p][dseg * 24];
#pragma unroll
    for (int j6 = 0; j6 < 6; ++j6) {
      uint4 u = *(const uint4*)(ur + j6 * 4);
      a0 = FDOT2(u.x, w0h[j6 * 4 + 0], a0); a1 = FDOT2(u.x, w1h[j6 * 4 + 0], a1);
      a0 = FDOT2(u.y, w0h[j6 * 4 + 1], a0); a1 = FDOT2(u.y, w1h[j6 * 4 + 1], a1);
      a0 = FDOT2(u.z, w0h[j6 * 4 + 2], a0); a1 = FDOT2(u.z, w1h[j6 * 4 + 2], a1);
      a0 = FDOT2(u.w, w0h[j6 * 4 + 3], a0); a1 = FDOT2(u.w, w1h[j6 * 4 + 3], a1);
    }
    a0 += __shfl_xor(a0, 1, 64); a0 += __shfl_xor(a0, 2, 64);
    a1 += __shfl_xor(a1, 1, 64); a1 += __shfl_xor(a1, 2, 64);
    if (dseg == 0 && active) {
      int l = l0 + p;
      od0[l] = a0;
      od1[LL - 1 - l] = a1;
    }
  }
}

// ---------------- 6a. scan phase A: serial aggregate, fp16 xg staging
__global__ __launch_bounds__(512) void k_scanA(const __half* __restrict__ xg0,
                                               const __half* __restrict__ xg1,
                                               const float* __restrict__ xdblT,
                                               const float* __restrict__ dtw,
                                               const float* __restrict__ dtb,
                                               const float* __restrict__ Alogs,
                                               float* __restrict__ Pbuf,
                                               float* __restrict__ Sbuf) {
  __shared__ float sX[22][PADL];     // rows 0..5 dts, 6..21 B
  __shared__ float sU[32][PADL];
  __shared__ float sDL[32][PADL];
  __shared__ float sDU[32][PADL];
  int blk = blockIdx.x;
  int cb = blk / NC, c = blk % NC;
  int bk = cb / 6, dg2 = cb % 6;
  int b = bk >> 2, k = bk & 3, d0 = dg2 * 32;
  int tid = threadIdx.x, ci = tid >> 4, n = tid & 15, d = d0 + ci;
  int l0 = c * LC;
  const __half* xg = (k & 1) ? xg1 : xg0;
  if (tid < 22 * 16) {
    int r = tid >> 4, c4 = tid & 15;
    float4 v = *(const float4*)(xdblT + ((size_t)(bk * C38 + r) * LL + l0 + c4 * 4));
    *(float4*)&sX[r][c4 * 4] = v;
  }
  float wr[6];
#pragma unroll
  for (int r = 0; r < 6; ++r) wr[r] = dtw[(size_t)(k * DI + d) * 6 + r];
  float bias = dtb[k * DI + d];
  float a2 = -__expf(Alogs[(size_t)(k * DI + d) * NS + n]) * LOG2E;
  for (int e = tid; e < LC * 16; e += 512) {
    int l = e >> 4, dq = e & 15;
    int ll = l0 + l;
    int ls = (k & 2) ? (LL - 1 - ll) : ll;
    __half2 hv = *(const __half2*)(xg + ((size_t)b * LL + ls) * DI + d0 + dq * 2);
    float2 fv = __half22float2(hv);
    sU[dq * 2][l] = fv.x;
    sU[dq * 2 + 1][l] = fv.y;
  }
  __syncthreads();
  float tsum = 0.f;
#pragma unroll
  for (int j = 0; j < 4; ++j) {
    int l = n + 16 * j;
    float acc = bias;
#pragma unroll
    for (int r = 0; r < 6; ++r) acc = fmaf(sX[r][l], wr[r], acc);
    float dl = softplusf(acc);
    sDL[ci][l] = dl;
    sDU[ci][l] = dl * sU[ci][l];
    tsum += dl;
  }
  tsum += __shfl_xor(tsum, 1, 64);
  tsum += __shfl_xor(tsum, 2, 64);
  tsum += __shfl_xor(tsum, 4, 64);
  tsum += __shfl_xor(tsum, 8, 64);
  float Pv = EXP2F(a2 * tsum);
  __syncthreads();
  float S = 0.f;
#pragma unroll 4
  for (int l4 = 0; l4 < 16; ++l4) {
    float4 DL4 = *(const float4*)&sDL[ci][l4 * 4];
    float4 DU4 = *(const float4*)&sDU[ci][l4 * 4];
    float4 B4  = *(const float4*)&sX[6 + n][l4 * 4];
    S = fmaf(S, EXP2F(DL4.x * a2), DU4.x * B4.x);
    S = fmaf(S, EXP2F(DL4.y * a2), DU4.y * B4.y);
    S = fmaf(S, EXP2F(DL4.z * a2), DU4.z * B4.z);
    S = fmaf(S, EXP2F(DL4.w * a2), DU4.w * B4.w);
  }
  int gid = ((size_t)bk * DI + d) * NS + n;
  Pbuf[(size_t)c * ST + gid] = Pv;
  Sbuf[(size_t)c * ST + gid] = S;
}

// ---------------- 6b. scan phase B (in-place) + pooled partial sums
__global__ __launch_bounds__(256) void k_scanB(const float* __restrict__ Pbuf,
                                               const float* __restrict__ Sbuf,
                                               float* __restrict__ Hbuf,
                                               const float* __restrict__ xc,
                                               float* __restrict__ partial) {
  if (blockIdx.x < ST / 256) {
    int gid = blockIdx.x * 256 + threadIdx.x;
    float h = 0.f;
    for (int c0 = 0; c0 < NC; c0 += 8) {
      float p[8], s[8];
#pragma unroll
      for (int j = 0; j < 8; ++j) {
        p[j] = Pbuf[(size_t)(c0 + j) * ST + gid];
        s[j] = Sbuf[(size_t)(c0 + j) * ST + gid];
      }
#pragma unroll
      for (int j = 0; j < 8; ++j) {
        Hbuf[(size_t)(c0 + j) * ST + gid] = h;
        h = fmaf(h, p[j], s[j]);
      }
    }
  } else {
    int blk = blockIdx.x - ST / 256;
    int b = blk >> 5; int s = blk & 31;
    int d = threadIdx.x;
    if (d < DI) {
      const float* p = xc + ((size_t)b * LL + s * 128) * DI + d;
      float acc = 0.f;
#pragma unroll 8
      for (int l = 0; l < 128; ++l) acc += p[(size_t)l * DI];
      partial[(size_t)blk * DI + d] = acc;
    }
  }
}

// ---------------- 6c. scan phase C (fp32 core, fp16 xg staging, fp16 output)
__global__ __launch_bounds__(512) void k_scanC(const __half* __restrict__ xg0,
                                               const __half* __restrict__ xg1,
                                               const float* __restrict__ xdblT,
                                               const float* __restrict__ dtw,
                                               const float* __restrict__ dtb,
                                               const float* __restrict__ Alogs,
                                               const float* __restrict__ Ds,
                                               const float* __restrict__ Hbuf,
                                               __half* __restrict__ outy) {
  __shared__ float sX[C38][PADL];    // 0..5 dts, 6..21 B, 22..37 C
  __shared__ float sU[32][PADL];
  __shared__ float sDL[32][PADL];
  __shared__ float sDU[32][PADL];
  int blk = blockIdx.x;
  int cb = blk / NC, c = blk % NC;
  int bk = cb / 6, dg2 = cb % 6;
  int b = bk >> 2, k = bk & 3, d0 = dg2 * 32;
  int tid = threadIdx.x, ci = tid >> 4, n = tid & 15, d = d0 + ci;
  int l0 = c * LC;
  const __half* xg = (k & 1) ? xg1 : xg0;
  for (int e = tid; e < C38 * 16; e += 512) {
    int r = e >> 4, c4 = e & 15;
    float4 v = *(const float4*)(xdblT + ((size_t)(bk * C38 + r) * LL + l0 + c4 * 4));
    *(float4*)&sX[r][c4 * 4] = v;
  }
  float wr[6];
#pragma unroll
  for (int r = 0; r < 6; ++r) wr[r] = dtw[(size_t)(k * DI + d) * 6 + r];
  float bias = dtb[k * DI + d];
  float a2 = -__expf(Alogs[(size_t)(k * DI + d) * NS + n]) * LOG2E;
  float Dv = Ds[k * DI + d];
  for (int e = tid; e < LC * 16; e += 512) {
    int l = e >> 4, dq = e & 15;
    int ll = l0 + l;
    int ls = (k & 2) ? (LL - 1 - ll) : ll;
    __half2 hv = *(const __half2*)(xg + ((size_t)b * LL + ls) * DI + d0 + dq * 2);
    float2 fv = __half22float2(hv);
    sU[dq * 2][l] = fv.x;
    sU[dq * 2 + 1][l] = fv.y;
  }
  __syncthreads();
#pragma unroll
  for (int j = 0; j < 4; ++j) {
    int l = n + 16 * j;
    float acc = bias;
#pragma unroll
    for (int r = 0; r < 6; ++r) acc = fmaf(sX[r][l], wr[r], acc);
    float dl = softplusf(acc);
    sDL[ci][l] = dl;
    sDU[ci][l] = dl * sU[ci][l];
  }
  __syncthreads();
  float h = Hbuf[(size_t)c * ST + ((size_t)bk * DI + d) * NS + n];
  bool k8 = (n & 8) != 0, k4 = (n & 4) != 0, k2 = (n & 2) != 0, k1 = (n & 1) != 0;
  __half* orow = outy + ((size_t)bk * LL + l0) * DI;
  for (int w16 = 0; w16 < 4; ++w16) {
    float acc[16];
#pragma unroll
    for (int q = 0; q < 4; ++q) {
      int l = w16 * 16 + q * 4;
      float4 DL4 = *(const float4*)&sDL[ci][l];
      float4 DU4 = *(const float4*)&sDU[ci][l];
      float4 B4  = *(const float4*)&sX[6 + n][l];
      float4 C4  = *(const float4*)&sX[22 + n][l];
      h = fmaf(h, EXP2F(DL4.x * a2), DU4.x * B4.x); acc[q * 4 + 0] = h * C4.x;
      h = fmaf(h, EXP2F(DL4.y * a2), DU4.y * B4.y); acc[q * 4 + 1] = h * C4.y;
      h = fmaf(h, EXP2F(DL4.z * a2), DU4.z * B4.z); acc[q * 4 + 2] = h * C4.z;
      h = fmaf(h, EXP2F(DL4.w * a2), DU4.w * B4.w); acc[q * 4 + 3] = h * C4.w;
    }
    float b8[8];
#pragma unroll
    for (int t = 0; t < 8; ++t) {
      float lo = acc[t], hi = acc[t + 8];
      float r = __shfl_xor(k8 ? lo : hi, 8, 64);
      b8[t] = (k8 ? hi : lo) + r;
    }
    float b4v[4];
#pragma unroll
    for (int t = 0; t < 4; ++t) {
      float lo = b8[t], hi = b8[t + 4];
      float r = __shfl_xor(k4 ? lo : hi, 4, 64);
      b4v[t] = (k4 ? hi : lo) + r;
    }
    float b2v[2];
#pragma unroll
    for (int t = 0; t < 2; ++t) {
      float lo = b4v[t], hi = b4v[t + 2];
      float r = __shfl_xor(k2 ? lo : hi, 2, 64);
      b2v[t] = (k2 ? hi : lo) + r;
    }
    float lo = b2v[0], hi = b2v[1];
    float r = __shfl_xor(k1 ? lo : hi, 1, 64);
    float y = (k1 ? hi : lo) + r;
    int lw = w16 * 16 + n;
    y = fmaf(sU[ci][lw], Dv, y);
    orow[(size_t)lw * DI + d0 + ci] = __float2half(y);
  }
}

// ---------------- 9+10. channel prep + scan + catt
__global__ __launch_bounds__(512) void k_ccomb(const float* __restrict__ partial,
                                               const float* __restrict__ cinw,
                                               const float* __restrict__ cinb,
                                               const float* __restrict__ xcw,
                                               const float* __restrict__ dtcw,
                                               const float* __restrict__ dtcb,
                                               const float* __restrict__ Aclogs,
                                               const float* __restrict__ Dsc,
                                               const float* __restrict__ coutw,
                                               const float* __restrict__ coutb,
                                               float* __restrict__ uc, float* __restrict__ dc,
                                               float* __restrict__ Bc, float* __restrict__ Cc,
                                               float* __restrict__ catt) {
  __shared__ float ycs[BSZ][2][4][DI];
  int t = threadIdx.x;
  for (int g = t; g < BSZ * 2 * DI; g += 512) {
    int l = g % DI; int k = (g / DI) & 1; int b = g / (2 * DI);
    int lsrc = k ? (DI - 1 - l) : l;
    float pv = 0.f;
#pragma unroll 8
    for (int s = 0; s < 32; ++s) pv += partial[(size_t)(b * 32 + s) * DI + lsrc];
    pv *= (1.f / 4096.f);
    float u[4];
#pragma unroll
    for (int i = 0; i < 4; ++i) u[i] = fmaf(pv, cinw[i], cinb[i]);
    int pos = (b * 2 + k) * DI + l;
    float db[C38];
#pragma unroll
    for (int c = 0; c < C38; ++c) {
      float s = 0.f;
#pragma unroll
      for (int i = 0; i < 4; ++i) s = fmaf(u[i], xcw[(k * C38 + c) * 4 + i], s);
      db[c] = s;
    }
#pragma unroll
    for (int i = 0; i < 4; ++i) uc[pos * 4 + i] = u[i];
#pragma unroll
    for (int i = 0; i < 4; ++i) {
      float tt = dtcb[k * 4 + i];
#pragma unroll
      for (int r = 0; r < 6; ++r) tt = fmaf(db[r], dtcw[(k * 4 + i) * 6 + r], tt);
      dc[pos * 4 + i] = softplusf(tt);
    }
#pragma unroll
    for (int n = 0; n < NS; ++n) Bc[pos * NS + n] = db[6 + n];
#pragma unroll
    for (int n = 0; n < NS; ++n) Cc[pos * NS + n] = db[22 + n];
  }
  __threadfence_block();
  __syncthreads();
  int chain = t >> 4;
  int n = t & 15;
  int b = chain >> 3; int k = (chain >> 2) & 1; int i = chain & 3;
  float a  = -__expf(Aclogs[(k * 4 + i) * NS + n]);
  float Dv = Dsc[k * 4 + i];
  const float* dp = dc + (size_t)((b * 2 + k) * DI) * 4 + i;
  const float* up = uc + (size_t)((b * 2 + k) * DI) * 4 + i;
  const float* bp = Bc + (size_t)((b * 2 + k) * DI) * NS + n;
  const float* cp = Cc + (size_t)((b * 2 + k) * DI) * NS + n;
  float h = 0.f;
  float qdA[8], quA[8], qbA[8], qcA[8];
  float qdB[8], quB[8], qbB[8], qcB[8];
#pragma unroll
  for (int j = 0; j < 8; ++j) {
    qdA[j] = dp[j * 4]; quA[j] = up[j * 4];
    qbA[j] = bp[j * 16]; qcA[j] = cp[j * 16];
  }
  for (int r = 0; r < 24; r += 2) {
    int lB = (r + 1) * 8;
#pragma unroll
    for (int j = 0; j < 8; ++j) {
      qdB[j] = dp[(lB + j) * 4]; quB[j] = up[(lB + j) * 4];
      qbB[j] = bp[(lB + j) * 16]; qcB[j] = cp[(lB + j) * 16];
    }
#pragma unroll
    for (int j = 0; j < 8; ++j) {
      float dl = qdA[j], ul = quA[j], Bv = qbA[j], Cv = qcA[j];
      h = fmaf(h, __expf(dl * a), dl * ul * Bv);
      float yv = h * Cv;
      yv += __shfl_xor(yv, 1, 64);
      yv += __shfl_xor(yv, 2, 64);
      yv += __shfl_xor(yv, 4, 64);
      yv += __shfl_xor(yv, 8, 64);
      if (n == 0) ycs[b][k][i][r * 8 + j] = yv + ul * Dv;
    }
    if (r + 2 < 24) {
      int lA = (r + 2) * 8;
#pragma unroll
      for (int j = 0; j < 8; ++j) {
        qdA[j] = dp[(lA + j) * 4]; quA[j] = up[(lA + j) * 4];
        qbA[j] = bp[(lA + j) * 16]; qcA[j] = cp[(lA + j) * 16];
      }
    }
#pragma unroll
    for (int j = 0; j < 8; ++j) {
      float dl = qdB[j], ul = quB[j], Bv = qbB[j], Cv = qcB[j];
      h = fmaf(h, __expf(dl * a), dl * ul * Bv);
      float yv = h * Cv;
      yv += __shfl_xor(yv, 1, 64);
      yv += __shfl_xor(yv, 2, 64);
      yv += __shfl_xor(yv, 4, 64);
      yv += __shfl_xor(yv, 8, 64);
      if (n == 0) ycs[b][k][i][(r + 1) * 8 + j] = yv + ul * Dv;
    }
  }
  __syncthreads();
  float cw[4];
#pragma unroll
  for (int q = 0; q < 4; ++q) cw[q] = coutw[q];
  float cb0 = coutb[0];
  for (int e = t; e < BSZ * DI; e += 512) {
    int bb = e / DI, ll = e % DI;
    float s = cb0;
#pragma unroll
    for (int q = 0; q < 4; ++q)
      s = fmaf(ycs[bb][0][q][ll] + ycs[bb][1][q][DI - 1 - ll], cw[q], s);
    catt[bb * DI + ll] = s;
  }
}

// ---------------- 11. final fuse (fp16 outy/z reads, weight-amortized out-proj)
__global__ __launch_bounds__(512) void k_final(const __half* __restrict__ outy,
                                               const float* __restrict__ xc,
                                               const __half* __restrict__ z,
                                               const float* __restrict__ catt,
                                               const float* __restrict__ onw,
                                               const float* __restrict__ onb,
                                               const float* __restrict__ cnw,
                                               const float* __restrict__ cnb,
                                               const float* __restrict__ WoutT,
                                               float* __restrict__ out) {
  __shared__ __align__(16) float sComb[8][DI + 4];
  int w = threadIdx.x >> 6, lane = threadIdx.x & 63;
  int p = blockIdx.x * 8 + w;
  int b = p >> 12, l = p & 4095;
  int lT = ((l & 63) << 6) | (l >> 6);
  size_t base = (size_t)b * KK * LL;
  const __half* r0 = outy + (base + l) * DI;
  const __half* r1 = outy + (base + 2 * LL + (LL - 1 - l)) * DI;
  const __half* r2 = outy + (base + LL + lT) * DI;
  const __half* r3 = outy + (base + 3 * LL + (LL - 1 - lT)) * DI;
  const float* xcr = xc + ((size_t)b * LL + l) * DI;
  const __half* zr = z + ((size_t)b * LL + l) * DI;
  const float* cattr = catt + b * DI;
  float ys[3], xch[3], zv[3];
  float s1 = 0.f, s2 = 0.f, t1 = 0.f, t2 = 0.f;
#pragma unroll
  for (int j = 0; j < 3; ++j) {
    int d = lane + 64 * j;
    float v = __half2float(r0[d]) + __half2float(r1[d])
            + __half2float(r2[d]) + __half2float(r3[d]);
    ys[j] = v; s1 += v; s2 += v * v;
    float xv = xcr[d] * cattr[d];
    xch[j] = xv; t1 += xv; t2 += xv * xv;
    zv[j] = __half2float(zr[d]);
  }
#pragma unroll
  for (int m = 1; m < 64; m <<= 1) {
    s1 += __shfl_xor(s1, m, 64);
    s2 += __shfl_xor(s2, m, 64);
    t1 += __shfl_xor(t1, m, 64);
    t2 += __shfl_xor(t2, m, 64);
  }
  float mu  = s1 * (1.f / DI);
  float var = s2 * (1.f / DI) - mu * mu;
  float rstd = rsqrtf(var + 1e-5f);
  float mu2  = t1 * (1.f / DI);
  float var2 = t2 * (1.f / DI) - mu2 * mu2;
  float rstd2 = rsqrtf(var2 + 1e-5f);
#pragma unroll
  for (int j = 0; j < 3; ++j) {
    int d = lane + 64 * j;
    float yln  = fmaf((ys[j] - mu) * rstd, onw[d], onb[d]);
    float xchn = fmaf((xch[j] - mu2) * rstd2, cnw[d], cnb[d]);
    sComb[w][d] = (yln + xchn) * siluf(zv[j]);
  }
  __syncthreads();
  if (threadIdx.x < DM) {
    int dm = threadIdx.x;
    float acc[8];
#pragma unroll
    for (int p8 = 0; p8 < 8; ++p8) acc[p8] = 0.f;
    for (int t = 0; t < DI; t += 4) {
      float w0 = WoutT[(size_t)(t + 0) * DM + dm];
      float w1 = WoutT[(size_t)(t + 1) * DM + dm];
      float w2 = WoutT[(size_t)(t + 2) * DM + dm];
      float w3 = WoutT[(size_t)(t + 3) * DM + dm];
#pragma unroll
      for (int p8 = 0; p8 < 8; ++p8) {
        float4 cv = *(const float4*)&sComb[p8][t];
        acc[p8] = fmaf(cv.x, w0, acc[p8]);
        acc[p8] = fmaf(cv.y, w1, acc[p8]);
        acc[p8] = fmaf(cv.z, w2, acc[p8]);
        acc[p8] = fmaf(cv.w, w3, acc[p8]);
      }
    }
#pragma unroll
    for (int p8 = 0; p8 < 8; ++p8)
      out[(size_t)(blockIdx.x * 8 + p8) * DM + dm] = acc[p8];
  }
}

extern "C" void kernel_launch(void* const* d_in, const int* in_sizes, int n_in,
                              void* d_out, int out_size, void* d_ws, size_t ws_size,
                              hipStream_t stream) {
  const float* x     = (const float*)d_in[0];
  const int*   xm    = (const int*)  d_in[1];
  const float* Win   = (const float*)d_in[2];
  const float* w3    = (const float*)d_in[3];
  const float* cbia  = (const float*)d_in[4];
  const float* xpw   = (const float*)d_in[5];
  const float* dtw   = (const float*)d_in[6];
  const float* dtb   = (const float*)d_in[7];
  const float* Alogs = (const float*)d_in[8];
  const float* Ds    = (const float*)d_in[9];
  const float* onw   = (const float*)d_in[10];
  const float* onb   = (const float*)d_in[11];
  const float* Wout  = (const float*)d_in[12];
  const float* cinw  = (const float*)d_in[13];
  const float* cinb  = (const float*)d_in[14];
  const float* coutw = (const float*)d_in[15];
  const float* coutb = (const float*)d_in[16];
  const float* xcw   = (const float*)d_in[17];
  const float* Dsc   = (const float*)d_in[18];
  const float* Aclog = (const float*)d_in[19];
  const float* dtcw  = (const float*)d_in[20];
  const float* dtcb  = (const float*)d_in[21];
  const float* cnw   = (const float*)d_in[22];
  const float* cnb   = (const float*)d_in[23];
  float* out = (float*)d_out;

  float* ws = (float*)d_ws;
  size_t o = 0;
  float* xdblT = ws + o; o += (size_t)BSZ * KK * C38 * LL;
  float* oyreg = ws + o; o += (size_t)BSZ * KK * LL * DI / 2;  // outy fp16 (25 MB)
  float* xc    = ws + o; o += (size_t)BSZ * LL * DI;
  float* zreg  = ws + o; o += (size_t)BSZ * LL * DI / 2;       // z fp16
  float* xg0r  = ws + o; o += (size_t)BSZ * LL * DI / 2;       // xg0 fp16
  float* xg1r  = ws + o; o += (size_t)BSZ * LL * DI / 2;       // xg1 fp16
  float* Sbuf  = ws + o; o += (size_t)NC * ST;
  float* partial = ws + o; o += BSZ * 32 * DI;
  float* uc    = ws + o; o += BSZ * 2 * DI * 4;
  float* dc    = ws + o; o += BSZ * 2 * DI * 4;
  float* Bc    = ws + o; o += BSZ * 2 * DI * NS;
  float* Cc    = ws + o; o += BSZ * 2 * DI * NS;
  float* catt  = ws + o; o += BSZ * DI;
  float* WinT  = ws + o; o += 384 * DM;
  float* WoutT = ws + o; o += DM * DI;
  int*   rnk   = (int*)(ws + o); o += BSZ * LL;
  __half* outy = (__half*)oyreg;
  __half* z    = (__half*)zreg;
  __half* xg0  = (__half*)xg0r;
  __half* xg1  = (__half*)xg1r;
  float* xh    = oyreg;            // alias: xh dead before k_scanC writes outy
  float* Pbuf  = oyreg;            // alias: Pbuf consumed by k_scanB before k_scanC writes outy
  float* Hbuf  = Sbuf;             // in-place exclusive scan

  int transBlocks = (384 * DM + DM * DI + 255) / 256;
  k_sorttrans<<<BSZ + transBlocks, 256, 0, stream>>>(xm, rnk, Win, Wout, WinT, WoutT);
  k_inproj<<<(BSZ * LL) / PPB, 384, 0, stream>>>(x, WinT, xh, z);
  k_conv  <<<BSZ * LL, 192, 0, stream>>>(xh, w3, cbia, rnk, xc, xg0, xg1);
  k_xdbl  <<<BSZ * 2 * 128, 192, 0, stream>>>(xg0, xg1, xpw, xdblT);
  k_scanA <<<96 * NC, 512, 0, stream>>>(xg0, xg1, xdblT, dtw, dtb, Alogs, Pbuf, Sbuf);
  k_scanB <<<ST / 256 + BSZ * 32, 256, 0, stream>>>(Pbuf, Sbuf, Hbuf, xc, partial);
  k_scanC <<<96 * NC, 512, 0, stream>>>(xg0, xg1, xdblT, dtw, dtb, Alogs, Ds, Hbuf, outy);
  k_ccomb <<<1, 512, 0, stream>>>(partial, cinw, cinb, xcw, dtcw, dtcb, Aclog, Dsc, coutw, coutb, uc, dc, Bc, Cc, catt);
  k_final <<<(BSZ * LL) / 8, 512, 0, stream>>>(outy, xc, z, catt, onw, onb, cnw, cnb, WoutT, out);
}